// Round 6
// baseline (31260.333 us; speedup 1.0000x reference)
//
#include <hip/hip_runtime.h>

#define NIN 7
#define NB 256
#define NS 2048

__device__ __forceinline__ float fastrcp(float x){ return __builtin_amdgcn_rcpf(x); }
__device__ __forceinline__ float sigf(float x){ return fastrcp(1.f + __expf(-x)); }
__device__ __forceinline__ float tanhf_(float x){ return 1.f - 2.f*fastrcp(1.f + __expf(2.f*x)); }

template<int J>
__device__ __forceinline__ float rlf(float v){
  return __uint_as_float((unsigned)__builtin_amdgcn_readlane((int)__float_as_uint(v), J));
}
__device__ __forceinline__ float rlfv(float v, int j){   // j must be compile-time after unroll
  return __uint_as_float((unsigned)__builtin_amdgcn_readlane((int)__float_as_uint(v), j));
}

#define FMA4(acc, B, v) { acc = fmaf(wreg[(B)+0],(v).x,acc); acc = fmaf(wreg[(B)+1],(v).y,acc); \
                          acc = fmaf(wreg[(B)+2],(v).z,acc); acc = fmaf(wreg[(B)+3],(v).w,acc); }

// MLP: q=relu(b1+W1 h) on rows lane&15 (h broadcast from lanes 0..31), d=b2+W2 q (q from lanes 0..15)
#define MLP(hval, M1B, B1, M2B, B2, dres) { \
  float q0_=wreg[B1], q1_=0.f; \
  _Pragma("unroll") \
  for (int j_=0;j_<32;j_+=2){ \
    q0_=fmaf(wreg[(M1B)+j_],   rlfv(hval,j_),   q0_); \
    q1_=fmaf(wreg[(M1B)+j_+1], rlfv(hval,j_+1), q1_); } \
  float qq_=fmaxf(q0_+q1_,0.f); \
  float e0_=wreg[B2], e1_=0.f; \
  _Pragma("unroll") \
  for (int j_=0;j_<16;j_+=2){ \
    e0_=fmaf(wreg[(M2B)+j_],   rlfv(qq_,j_),   e0_); \
    e1_=fmaf(wreg[(M2B)+j_+1], rlfv(qq_,j_+1), e1_); } \
  dres=e0_+e1_; }

__global__ __launch_bounds__(512, 1) void mtinn_kernel(
    const float* __restrict__ x,
    const float* wihs, const float* whhs, const float* bihs, const float* bhhs,
    const float* wiha, const float* whha, const float* biha, const float* bhha,
    const float* wihv, const float* whhv, const float* bihv, const float* bhhv,
    const float* wihp, const float* whhp, const float* bihp, const float* bhhp,
    const float* wa1, const float* ba1, const float* wa2, const float* ba2,
    const float* wv1, const float* bv1, const float* wv2, const float* bv2,
    const float* wp1, const float* bp1, const float* wp2, const float* bp2,
    float* __restrict__ out)
{
  __shared__ __align__(16) float ZS[2][256];                 // shared-cell z, double buffered
  __shared__ __align__(16) float ZATT[128], ZVEL[128], ZPOS[128];
  __shared__ __align__(16) float HA[32], HV[32], HP[32];     // h_a/h_v/h_p(t)
  __shared__ __align__(16) float HSs[8][64];                 // per-wave hs broadcast copies
  __shared__ __align__(16) float XL[4][8];                   // x ring; slot[7] = 1.0 (bias trick)

  const int tid  = threadIdx.x;
  const int wave = tid >> 6, lane = tid & 63;
  const int b    = blockIdx.x;
  const float* xb = x + (size_t)b * NS * NIN;

  // ---- overlaid per-lane register weights (max 176 floats) ----
  // w1/w2 (att rows r=(wave-1)*64+lane), w3/w4 (vel), w5/w6 (pos):
  //   [0..63] hs-w | [64..70] x-w (pos: 0) | [71] bias | [72..103] hh-w
  // w2/w5/w6/w7 additionally one shared row: [104..167] hs | [168..174] x | [175] bias
  // w0: [0..32] m1a | [33..65] m1v | [66..98] m1p | [99..115] m2a | [116..132] m2v |
  //     [133..149] m2p | [150..161] vel d-cols (i,f,g,o x3) | [162..173] pos d-cols
  float wreg[176];
#pragma unroll
  for (int i = 0; i < 176; i++) wreg[i] = 0.f;

  if (wave == 1 || wave == 2){
    const int r = (wave-1)*64 + lane;
#pragma unroll
    for (int k=0;k<64;k++) wreg[k]    = wiha[r*71+k];
#pragma unroll
    for (int k=0;k<7;k++)  wreg[64+k] = wiha[r*71+64+k];
    wreg[71] = biha[r] + bhha[r];
#pragma unroll
    for (int k=0;k<32;k++) wreg[72+k] = whha[r*32+k];
  } else if (wave == 3 || wave == 4){
    const int r = (wave-3)*64 + lane;
#pragma unroll
    for (int k=0;k<64;k++) wreg[k]    = wihv[r*74+k];
#pragma unroll
    for (int k=0;k<7;k++)  wreg[64+k] = wihv[r*74+67+k];
    wreg[71] = bihv[r] + bhhv[r];
#pragma unroll
    for (int k=0;k<32;k++) wreg[72+k] = whhv[r*32+k];
  } else if (wave == 5 || wave == 6){
    const int r = (wave-5)*64 + lane;
#pragma unroll
    for (int k=0;k<64;k++) wreg[k]    = wihp[r*67+k];
    wreg[71] = bihp[r] + bhhp[r];                      // x-w stay 0
#pragma unroll
    for (int k=0;k<32;k++) wreg[72+k] = whhp[r*32+k];
  }
  if (wave == 2 || wave >= 5){                         // shared rows: w2=i, w5=f, w6=g, w7=o
    const int q = (wave==2) ? 0 : (wave-4);
    const int r = q*64 + lane;
#pragma unroll
    for (int k=0;k<64;k++) wreg[104+k] = whhs[r*64+k];
#pragma unroll
    for (int k=0;k<7;k++)  wreg[168+k] = wihs[r*7+k];
    wreg[175] = bihs[r] + bhhs[r];
  }
  if (wave == 0){
    const int mi = lane & 15, mm = lane % 3, l = lane & 31;
#pragma unroll
    for (int k=0;k<32;k++){ wreg[k]=wa1[mi*32+k]; wreg[33+k]=wv1[mi*32+k]; wreg[66+k]=wp1[mi*32+k]; }
    wreg[32]=ba1[mi]; wreg[65]=bv1[mi]; wreg[98]=bp1[mi];
#pragma unroll
    for (int k=0;k<16;k++){ wreg[99+k]=wa2[mm*16+k]; wreg[116+k]=wv2[mm*16+k]; wreg[133+k]=wp2[mm*16+k]; }
    wreg[115]=ba2[mm]; wreg[132]=bv2[mm]; wreg[149]=bp2[mm];
#pragma unroll
    for (int g=0; g<4; g++)
#pragma unroll
      for (int k=0;k<3;k++){
        wreg[150+g*3+k] = wihv[(g*32+l)*74+64+k];
        wreg[162+g*3+k] = wihp[(g*32+l)*67+64+k];
      }
  }

  // ---- LDS init ----
  if (tid < 32) HA[tid]=0.f; else if (tid < 64) HV[tid-32]=0.f; else if (tid < 96) HP[tid-64]=0.f;
  if (tid < 8){
    XL[0][tid] = (tid<7) ? xb[tid]        : 1.f;
    XL[1][tid] = (tid<7) ? xb[NIN+tid]    : 1.f;
    XL[2][tid] = (tid<7) ? xb[2*NIN+tid]  : 1.f;
    XL[3][tid] = 1.f;
  }
  __syncthreads();

  // ---- prologue: zS(0) ----
  if (wave == 2 || wave >= 5){
    const int qoff = ((wave==2) ? 0 : (wave-4))*64;
    float4 x0 = ((const float4*)XL[0])[0], x1 = ((const float4*)XL[0])[1];
    float s = 0.f; FMA4(s,168,x0); FMA4(s,172,x1);     // includes bias via XL[7]=1
    ZS[0][qoff+lane] = s;
  }
  __syncthreads();

  float c_s=0.f, c_a=0.f, c_v=0.f, c_p=0.f;
  float zpart = 0.f;

  // ---- prologue: hs(0), z-partials(0), zS(1) ----
  if (wave >= 1){
    float zi=ZS[0][lane], zf=ZS[0][64+lane], zg=ZS[0][128+lane], zo=ZS[0][192+lane];
    c_s = sigf(zf)*c_s + sigf(zi)*tanhf_(zg);
    float hsv = sigf(zo)*tanhf_(c_s);
    HSs[wave][lane] = hsv;
    const float4* H4 = (const float4*)HSs[wave];
    if (wave == 2 || wave >= 5){
      float a0=0.f,a1=0.f,s0=0.f,s1=0.f;
#pragma unroll
      for (int c=0;c<16;c++){
        float4 h = H4[c];
        if (c&1){ FMA4(a1,4*c,h); FMA4(s1,104+4*c,h); }
        else    { FMA4(a0,4*c,h); FMA4(s0,104+4*c,h); }
      }
      float4 xa=((const float4*)XL[0])[0], xb4=((const float4*)XL[0])[1];
      FMA4(a0,64,xa); FMA4(a1,68,xb4);
      zpart = a0+a1;                                    // garbage on w7 (wreg[0..71]=0) - unused
      float4 xc=((const float4*)XL[1])[0], xd=((const float4*)XL[1])[1];
      FMA4(s0,168,xc); FMA4(s1,172,xd);
      const int qoff = ((wave==2) ? 0 : (wave-4))*64;
      ZS[1][qoff+lane] = s0+s1;
    } else {
      float a0=0.f,a1=0.f;
#pragma unroll
      for (int c=0;c<16;c++){
        float4 h = H4[c];
        if (c&1){ FMA4(a1,4*c,h); } else { FMA4(a0,4*c,h); }
      }
      float4 xa=((const float4*)XL[0])[0], xb4=((const float4*)XL[0])[1];
      FMA4(a0,64,xa); FMA4(a1,68,xb4);
      zpart = a0+a1;
    }
  }

  // ================= pipelined recurrence =================
#pragma unroll 1
  for (int t = 0; t < NS; t++){
    // ---- TOP: finish z(t) = zpart + Whh·h(t-1) ----
    if (wave >= 1 && wave <= 6){
      const float* Hsrc = (wave<=2) ? HA : (wave<=4 ? HV : HP);
      const float4* H4 = (const float4*)Hsrc;
      float z0 = zpart, z1 = 0.f;
      float4 h0=H4[0],h1=H4[1],h2=H4[2],h3=H4[3],h4=H4[4],h5=H4[5],h6=H4[6],h7=H4[7];
      FMA4(z0,72,h0); FMA4(z1,76,h1); FMA4(z0,80,h2); FMA4(z1,84,h3);
      FMA4(z0,88,h4); FMA4(z1,92,h5); FMA4(z0,96,h6); FMA4(z1,100,h7);
      float* Zd = (wave<=2) ? ZATT : (wave<=4 ? ZVEL : ZPOS);
      Zd[((wave-1)&1)*64 + lane] = z0+z1;
    }
    __syncthreads();   // #1 : z(t) visible to wave 0; ZS[(t+1)&1] visible to all

    if (wave == 0){
      // ================= TAIL(t) =================
      __builtin_amdgcn_s_setprio(1);
      const int l = lane & 31;
      float zai=ZATT[l], zaf=ZATT[32+l], zag=ZATT[64+l], zao=ZATT[96+l];
      float zvi=ZVEL[l], zvf=ZVEL[32+l], zvg=ZVEL[64+l], zvo=ZVEL[96+l];
      float zpi=ZPOS[l], zpf=ZPOS[32+l], zpg=ZPOS[64+l], zpo=ZPOS[96+l];
      float* ob = out + ((size_t)b*NS + t)*9;
      // ATT
      c_a = sigf(zaf)*c_a + sigf(zai)*tanhf_(zag);
      float ha = sigf(zao)*tanhf_(c_a);
      if (lane < 32) HA[lane] = ha;
      float dA; MLP(ha, 0, 32, 99, 115, dA);
      if (lane < 3) ob[lane] = dA;
      float dx=rlf<0>(dA), dy=rlf<1>(dA), dz=rlf<2>(dA);
      // VEL (+ d_att columns)
      zvi = fmaf(wreg[150],dx, fmaf(wreg[151],dy, fmaf(wreg[152],dz, zvi)));
      zvf = fmaf(wreg[153],dx, fmaf(wreg[154],dy, fmaf(wreg[155],dz, zvf)));
      zvg = fmaf(wreg[156],dx, fmaf(wreg[157],dy, fmaf(wreg[158],dz, zvg)));
      zvo = fmaf(wreg[159],dx, fmaf(wreg[160],dy, fmaf(wreg[161],dz, zvo)));
      c_v = sigf(zvf)*c_v + sigf(zvi)*tanhf_(zvg);
      float hv = sigf(zvo)*tanhf_(c_v);
      if (lane < 32) HV[lane] = hv;
      float dV; MLP(hv, 33, 65, 116, 132, dV);
      if (lane < 3) ob[3+lane] = dV;
      dx=rlf<0>(dV); dy=rlf<1>(dV); dz=rlf<2>(dV);
      // POS (+ d_vel columns)
      zpi = fmaf(wreg[162],dx, fmaf(wreg[163],dy, fmaf(wreg[164],dz, zpi)));
      zpf = fmaf(wreg[165],dx, fmaf(wreg[166],dy, fmaf(wreg[167],dz, zpf)));
      zpg = fmaf(wreg[168],dx, fmaf(wreg[169],dy, fmaf(wreg[170],dz, zpg)));
      zpo = fmaf(wreg[171],dx, fmaf(wreg[172],dy, fmaf(wreg[173],dz, zpo)));
      c_p = sigf(zpf)*c_p + sigf(zpi)*tanhf_(zpg);
      float hp_ = sigf(zpo)*tanhf_(c_p);
      if (lane < 32) HP[lane] = hp_;
      float dP; MLP(hp_, 66, 98, 133, 149, dP);
      if (lane < 3) ob[6+lane] = dP;
      __builtin_amdgcn_s_setprio(0);
    } else {
      // ============ WINDOW(t): hs(t+1) + dot partials for t+1 + zS(t+2) ============
      const int tn1 = (t+1)&3, tn2 = (t+2)&3;
      float xpre = 0.f;
      if (wave == 7 && lane < 7){
        const int tf = (t+3 < NS) ? t+3 : NS-1;
        xpre = xb[(size_t)tf*NIN + lane];
      }
      const float* Zsrc = ZS[(t+1)&1];
      float zi=Zsrc[lane], zf=Zsrc[64+lane], zg=Zsrc[128+lane], zo=Zsrc[192+lane];
      c_s = sigf(zf)*c_s + sigf(zi)*tanhf_(zg);
      float hsv = sigf(zo)*tanhf_(c_s);
      HSs[wave][lane] = hsv;
      const float4* H4 = (const float4*)HSs[wave];
      if (wave == 2 || wave >= 5){
        float a0=0.f,a1=0.f,s0=0.f,s1=0.f;
#pragma unroll
        for (int c=0;c<16;c++){
          float4 h = H4[c];
          if (c&1){ FMA4(a1,4*c,h); FMA4(s1,104+4*c,h); }
          else    { FMA4(a0,4*c,h); FMA4(s0,104+4*c,h); }
        }
        float4 xa=((const float4*)XL[tn1])[0], xb4=((const float4*)XL[tn1])[1];
        FMA4(a0,64,xa); FMA4(a1,68,xb4);
        zpart = a0+a1;
        float4 xc=((const float4*)XL[tn2])[0], xd=((const float4*)XL[tn2])[1];
        FMA4(s0,168,xc); FMA4(s1,172,xd);
        const int qoff = ((wave==2) ? 0 : (wave-4))*64;
        ZS[t&1][qoff+lane] = s0+s1;
      } else {
        float a0=0.f,a1=0.f;
#pragma unroll
        for (int c=0;c<16;c++){
          float4 h = H4[c];
          if (c&1){ FMA4(a1,4*c,h); } else { FMA4(a0,4*c,h); }
        }
        float4 xa=((const float4*)XL[tn1])[0], xb4=((const float4*)XL[tn1])[1];
        FMA4(a0,64,xa); FMA4(a1,68,xb4);
        zpart = a0+a1;
      }
      if (wave == 7 && lane < 7) XL[(t+3)&3][lane] = xpre;
    }
    __syncthreads();   // #2 : h(t), out done; next iteration may overwrite
  }
}

extern "C" void kernel_launch(void* const* d_in, const int* in_sizes, int n_in,
                              void* d_out, int out_size, void* d_ws, size_t ws_size,
                              hipStream_t stream) {
  (void)in_sizes; (void)n_in; (void)d_ws; (void)ws_size; (void)out_size;
  const float* X    = (const float*)d_in[0];
  const float* Wihs = (const float*)d_in[1];
  const float* Whhs = (const float*)d_in[2];
  const float* Bihs = (const float*)d_in[3];
  const float* Bhhs = (const float*)d_in[4];
  const float* Wiha = (const float*)d_in[5];
  const float* Whha = (const float*)d_in[6];
  const float* Biha = (const float*)d_in[7];
  const float* Bhha = (const float*)d_in[8];
  const float* Wihv = (const float*)d_in[9];
  const float* Whhv = (const float*)d_in[10];
  const float* Bihv = (const float*)d_in[11];
  const float* Bhhv = (const float*)d_in[12];
  const float* Wihp = (const float*)d_in[13];
  const float* Whhp = (const float*)d_in[14];
  const float* Bihp = (const float*)d_in[15];
  const float* Bhhp = (const float*)d_in[16];
  const float* Wa1  = (const float*)d_in[17];
  const float* Ba1  = (const float*)d_in[18];
  const float* Wa2  = (const float*)d_in[19];
  const float* Ba2  = (const float*)d_in[20];
  const float* Wv1  = (const float*)d_in[21];
  const float* Bv1  = (const float*)d_in[22];
  const float* Wv2  = (const float*)d_in[23];
  const float* Bv2  = (const float*)d_in[24];
  const float* Wp1  = (const float*)d_in[25];
  const float* Bp1  = (const float*)d_in[26];
  const float* Wp2  = (const float*)d_in[27];
  const float* Bp2  = (const float*)d_in[28];
  float* OUTP = (float*)d_out;

  mtinn_kernel<<<dim3(NB), dim3(512), 0, stream>>>(
      X, Wihs, Whhs, Bihs, Bhhs,
      Wiha, Whha, Biha, Bhha,
      Wihv, Whhv, Bihv, Bhhv,
      Wihp, Whhp, Bihp, Bhhp,
      Wa1, Ba1, Wa2, Ba2, Wv1, Bv1, Wv2, Bv2, Wp1, Bp1, Wp2, Bp2,
      OUTP);
}

// Round 7
// 4733.481 us; speedup vs baseline: 6.6041x; 6.6041x over previous
//
#include <hip/hip_runtime.h>

typedef unsigned int u32;

#define NIN 7
#define NB 256
#define NS 2048

__device__ __forceinline__ float fastrcp(float x){ return __builtin_amdgcn_rcpf(x); }
__device__ __forceinline__ float sigf(float x){ return fastrcp(1.f + __expf(-x)); }
__device__ __forceinline__ float tanhf_(float x){ return 1.f - 2.f*fastrcp(1.f + __expf(2.f*x)); }

__device__ __forceinline__ float blo(u32 u){ return __uint_as_float(u << 16); }
__device__ __forceinline__ float bhi(u32 u){ return __uint_as_float(u & 0xffff0000u); }
__device__ __forceinline__ u32 f2b(float f){            // RNE to bf16 (16-bit result)
  u32 x = __float_as_uint(f);
  return (x + 0x7fffu + ((x >> 16) & 1u)) >> 16;
}
__device__ __forceinline__ u32 pkb(float a, float b){ return f2b(a) | (f2b(b) << 16); }

template<int J>
__device__ __forceinline__ float rlf(float v){
  return __uint_as_float((unsigned)__builtin_amdgcn_readlane((int)__float_as_uint(v), J));
}
__device__ __forceinline__ float rlfv(float v, int j){   // j compile-time after unroll
  return __uint_as_float((unsigned)__builtin_amdgcn_readlane((int)__float_as_uint(v), j));
}

// acc pair += w[K],w[K+1] (4 bf16) dot float4 v
#define FMAP(a0, a1, K, v) { \
  u32 u0_ = w[(K)], u1_ = w[(K)+1]; \
  a0 = fmaf(blo(u0_), (v).x, a0); a1 = fmaf(bhi(u0_), (v).y, a1); \
  a0 = fmaf(blo(u1_), (v).z, a0); a1 = fmaf(bhi(u1_), (v).w, a1); }

// MLP: q=relu(b1 + W1 h) rows lane&15 (h from lanes 0..31), d=b2 + W2 q (q from lanes 0..15)
#define MLPP(hval, M1B, B1V, M2B, B2V, dres) { \
  float q0_ = (B1V), q1_ = 0.f; \
  _Pragma("unroll") \
  for (int j_ = 0; j_ < 16; j_++){ \
    u32 m_ = w[(M1B)+j_]; \
    q0_ = fmaf(blo(m_), rlfv(hval, 2*j_),   q0_); \
    q1_ = fmaf(bhi(m_), rlfv(hval, 2*j_+1), q1_); } \
  float qq_ = fmaxf(q0_+q1_, 0.f); \
  float e0_ = (B2V), e1_ = 0.f; \
  _Pragma("unroll") \
  for (int j_ = 0; j_ < 8; j_++){ \
    u32 m_ = w[(M2B)+j_]; \
    e0_ = fmaf(blo(m_), rlfv(qq_, 2*j_),   e0_); \
    e1_ = fmaf(bhi(m_), rlfv(qq_, 2*j_+1), e1_); } \
  dres = e0_ + e1_; }

__global__ __launch_bounds__(512, 1) void mtinn_kernel(
    const float* __restrict__ x,
    const float* wihs, const float* whhs, const float* bihs, const float* bhhs,
    const float* wiha, const float* whha, const float* biha, const float* bhha,
    const float* wihv, const float* whhv, const float* bihv, const float* bhhv,
    const float* wihp, const float* whhp, const float* bihp, const float* bhhp,
    const float* wa1, const float* ba1, const float* wa2, const float* ba2,
    const float* wv1, const float* bv1, const float* wv2, const float* bv2,
    const float* wp1, const float* bp1, const float* wp2, const float* bp2,
    float* __restrict__ out)
{
  __shared__ __align__(16) float ZS[2][256];                 // shared-cell z, double buffered
  __shared__ __align__(16) float ZATT[128], ZVEL[128], ZPOS[128];
  __shared__ __align__(16) float HA[32], HV[32], HP[32];     // h_a/h_v/h_p(t)
  __shared__ __align__(16) float HSs[8][64];                 // per-wave hs broadcast copies
  __shared__ __align__(16) float XL[4][8];                   // x ring; slot[7] = 1.0 (bias trick)

  const int tid  = threadIdx.x;
  const int wave = tid >> 6, lane = tid & 63;
  const int b    = blockIdx.x;
  const float* xb = x + (size_t)b * NS * NIN;

  // ---- packed bf16 register weights (u32 = 2 weights), max 92/lane ----
  // waves 1-6 (cell row): [0..31] hs | [32..35] x+bias | [36..51] hh
  // waves 2,5,6,7 (+1 shared row): [52..83] hs | [84..87] x+bias
  // wave 0: [0..15] m1a | [16..31] m1v | [32..47] m1p | [48..55] m2a | [56..63] m2v |
  //         [64..71] m2p | [72..79] velD | [80..87] posD | [89..91] biases (b1|b2)
  u32 w[92];
#pragma unroll
  for (int i = 0; i < 92; i++) w[i] = 0u;

  if (wave == 1 || wave == 2){
    const int r = (wave-1)*64 + lane;
#pragma unroll
    for (int k=0;k<32;k++) w[k] = pkb(wiha[r*71+2*k], wiha[r*71+2*k+1]);
    w[32]=pkb(wiha[r*71+64],wiha[r*71+65]);
    w[33]=pkb(wiha[r*71+66],wiha[r*71+67]);
    w[34]=pkb(wiha[r*71+68],wiha[r*71+69]);
    w[35]=pkb(wiha[r*71+70], biha[r]+bhha[r]);
#pragma unroll
    for (int k=0;k<16;k++) w[36+k] = pkb(whha[r*32+2*k], whha[r*32+2*k+1]);
  } else if (wave == 3 || wave == 4){
    const int r = (wave-3)*64 + lane;
#pragma unroll
    for (int k=0;k<32;k++) w[k] = pkb(wihv[r*74+2*k], wihv[r*74+2*k+1]);
    w[32]=pkb(wihv[r*74+67],wihv[r*74+68]);
    w[33]=pkb(wihv[r*74+69],wihv[r*74+70]);
    w[34]=pkb(wihv[r*74+71],wihv[r*74+72]);
    w[35]=pkb(wihv[r*74+73], bihv[r]+bhhv[r]);
#pragma unroll
    for (int k=0;k<16;k++) w[36+k] = pkb(whhv[r*32+2*k], whhv[r*32+2*k+1]);
  } else if (wave == 5 || wave == 6){
    const int r = (wave-5)*64 + lane;
#pragma unroll
    for (int k=0;k<32;k++) w[k] = pkb(wihp[r*67+2*k], wihp[r*67+2*k+1]);
    w[35]=pkb(0.f, bihp[r]+bhhp[r]);                 // no x-weights for pos
#pragma unroll
    for (int k=0;k<16;k++) w[36+k] = pkb(whhp[r*32+2*k], whhp[r*32+2*k+1]);
  }
  if (wave == 2 || wave >= 5){                       // shared rows: w2=i, w5=f, w6=g, w7=o
    const int q = (wave==2) ? 0 : (wave-4);
    const int r = q*64 + lane;
#pragma unroll
    for (int k=0;k<32;k++) w[52+k] = pkb(whhs[r*64+2*k], whhs[r*64+2*k+1]);
    w[84]=pkb(wihs[r*7+0],wihs[r*7+1]);
    w[85]=pkb(wihs[r*7+2],wihs[r*7+3]);
    w[86]=pkb(wihs[r*7+4],wihs[r*7+5]);
    w[87]=pkb(wihs[r*7+6], bihs[r]+bhhs[r]);
  }
  if (wave == 0){
    const int mi = lane & 15, mm = lane % 3, l = lane & 31;
#pragma unroll
    for (int k=0;k<16;k++){
      w[k]    = pkb(wa1[mi*32+2*k], wa1[mi*32+2*k+1]);
      w[16+k] = pkb(wv1[mi*32+2*k], wv1[mi*32+2*k+1]);
      w[32+k] = pkb(wp1[mi*32+2*k], wp1[mi*32+2*k+1]);
    }
#pragma unroll
    for (int k=0;k<8;k++){
      w[48+k] = pkb(wa2[mm*16+2*k], wa2[mm*16+2*k+1]);
      w[56+k] = pkb(wv2[mm*16+2*k], wv2[mm*16+2*k+1]);
      w[64+k] = pkb(wp2[mm*16+2*k], wp2[mm*16+2*k+1]);
    }
#pragma unroll
    for (int g=0; g<4; g++){
      w[72+2*g]   = pkb(wihv[(g*32+l)*74+64], wihv[(g*32+l)*74+65]);
      w[72+2*g+1] = pkb(wihv[(g*32+l)*74+66], 0.f);
      w[80+2*g]   = pkb(wihp[(g*32+l)*67+64], wihp[(g*32+l)*67+65]);
      w[80+2*g+1] = pkb(wihp[(g*32+l)*67+66], 0.f);
    }
    w[89]=pkb(ba1[mi], ba2[mm]); w[90]=pkb(bv1[mi], bv2[mm]); w[91]=pkb(bp1[mi], bp2[mm]);
  }

  // ---- LDS init ----
  if (tid < 32) HA[tid]=0.f; else if (tid < 64) HV[tid-32]=0.f; else if (tid < 96) HP[tid-64]=0.f;
  if (tid < 8){
    XL[0][tid] = (tid<7) ? xb[tid]        : 1.f;
    XL[1][tid] = (tid<7) ? xb[NIN+tid]    : 1.f;
    XL[2][tid] = (tid<7) ? xb[2*NIN+tid]  : 1.f;
    XL[3][tid] = 1.f;
  }
  __syncthreads();

  // ---- prologue: zS(0) = b + Wih x(0) ----
  if (wave == 2 || wave >= 5){
    const int qoff = ((wave==2) ? 0 : (wave-4))*64;
    float4 x0 = ((const float4*)XL[0])[0], x1 = ((const float4*)XL[0])[1];
    float s0=0.f, s1=0.f; FMAP(s0,s1,84,x0); FMAP(s0,s1,86,x1);
    ZS[0][qoff+lane] = s0+s1;
  }
  __syncthreads();

  float c_s=0.f, c_a=0.f, c_v=0.f, c_p=0.f;
  float zpart = 0.f;

  // ---- prologue: hs(0), z-partials(0), zS(1) ----
  if (wave >= 1){
    float zi=ZS[0][lane], zf=ZS[0][64+lane], zg=ZS[0][128+lane], zo=ZS[0][192+lane];
    c_s = sigf(zf)*c_s + sigf(zi)*tanhf_(zg);
    float hsv = sigf(zo)*tanhf_(c_s);
    HSs[wave][lane] = hsv;
    const float4* H4 = (const float4*)HSs[wave];
    if (wave == 2 || wave >= 5){
      float a0=0.f,a1=0.f,s0=0.f,s1=0.f;
#pragma unroll
      for (int c=0;c<16;c++){
        float4 h = H4[c];
        FMAP(a0,a1,2*c,h); FMAP(s0,s1,52+2*c,h);
      }
      float4 xa=((const float4*)XL[0])[0], xb4=((const float4*)XL[0])[1];
      FMAP(a0,a1,32,xa); FMAP(a0,a1,34,xb4);
      zpart = a0+a1;                                  // w7: zeros -> unused
      float4 xc=((const float4*)XL[1])[0], xd=((const float4*)XL[1])[1];
      FMAP(s0,s1,84,xc); FMAP(s0,s1,86,xd);
      const int qoff = ((wave==2) ? 0 : (wave-4))*64;
      ZS[1][qoff+lane] = s0+s1;
    } else {
      float a0=0.f,a1=0.f;
#pragma unroll
      for (int c=0;c<16;c++){ float4 h = H4[c]; FMAP(a0,a1,2*c,h); }
      float4 xa=((const float4*)XL[0])[0], xb4=((const float4*)XL[0])[1];
      FMAP(a0,a1,32,xa); FMAP(a0,a1,34,xb4);
      zpart = a0+a1;
    }
  }

  // ================= pipelined recurrence =================
#pragma unroll 1
  for (int t = 0; t < NS; t++){
    // ---- TOP: finish z(t) = zpart + Whh·h(t-1) ----
    if (wave >= 1 && wave <= 6){
      const float* Hsrc = (wave<=2) ? HA : (wave<=4 ? HV : HP);
      const float4* H4 = (const float4*)Hsrc;
      float z0 = zpart, z1 = 0.f;
#pragma unroll
      for (int c=0;c<8;c++){ FMAP(z0,z1,36+2*c,H4[c]); }
      float* Zd = (wave<=2) ? ZATT : (wave<=4 ? ZVEL : ZPOS);
      Zd[((wave-1)&1)*64 + lane] = z0+z1;
    }
    __syncthreads();   // #1 : z(t) visible to wave 0; ZS[(t+1)&1] visible to all

    if (wave == 0){
      // ================= TAIL(t) =================
      __builtin_amdgcn_s_setprio(1);
      const int l = lane & 31;
      float zai=ZATT[l], zaf=ZATT[32+l], zag=ZATT[64+l], zao=ZATT[96+l];
      float zvi=ZVEL[l], zvf=ZVEL[32+l], zvg=ZVEL[64+l], zvo=ZVEL[96+l];
      float zpi=ZPOS[l], zpf=ZPOS[32+l], zpg=ZPOS[64+l], zpo=ZPOS[96+l];
      float* ob = out + ((size_t)b*NS + t)*9;
      // ATT
      c_a = sigf(zaf)*c_a + sigf(zai)*tanhf_(zag);
      float ha = sigf(zao)*tanhf_(c_a);
      if (lane < 32) HA[lane] = ha;
      float dA; MLPP(ha, 0, blo(w[89]), 48, bhi(w[89]), dA);
      if (lane < 3) ob[lane] = dA;
      float dx=rlf<0>(dA), dy=rlf<1>(dA), dz=rlf<2>(dA);
      // VEL (+ d_att columns)
      zvi = fmaf(blo(w[72]),dx, fmaf(bhi(w[72]),dy, fmaf(blo(w[73]),dz, zvi)));
      zvf = fmaf(blo(w[74]),dx, fmaf(bhi(w[74]),dy, fmaf(blo(w[75]),dz, zvf)));
      zvg = fmaf(blo(w[76]),dx, fmaf(bhi(w[76]),dy, fmaf(blo(w[77]),dz, zvg)));
      zvo = fmaf(blo(w[78]),dx, fmaf(bhi(w[78]),dy, fmaf(blo(w[79]),dz, zvo)));
      c_v = sigf(zvf)*c_v + sigf(zvi)*tanhf_(zvg);
      float hv = sigf(zvo)*tanhf_(c_v);
      if (lane < 32) HV[lane] = hv;
      float dV; MLPP(hv, 16, blo(w[90]), 56, bhi(w[90]), dV);
      if (lane < 3) ob[3+lane] = dV;
      dx=rlf<0>(dV); dy=rlf<1>(dV); dz=rlf<2>(dV);
      // POS (+ d_vel columns)
      zpi = fmaf(blo(w[80]),dx, fmaf(bhi(w[80]),dy, fmaf(blo(w[81]),dz, zpi)));
      zpf = fmaf(blo(w[82]),dx, fmaf(bhi(w[82]),dy, fmaf(blo(w[83]),dz, zpf)));
      zpg = fmaf(blo(w[84]),dx, fmaf(bhi(w[84]),dy, fmaf(blo(w[85]),dz, zpg)));
      zpo = fmaf(blo(w[86]),dx, fmaf(bhi(w[86]),dy, fmaf(blo(w[87]),dz, zpo)));
      c_p = sigf(zpf)*c_p + sigf(zpi)*tanhf_(zpg);
      float hp_ = sigf(zpo)*tanhf_(c_p);
      if (lane < 32) HP[lane] = hp_;
      float dP; MLPP(hp_, 32, blo(w[91]), 64, bhi(w[91]), dP);
      if (lane < 3) ob[6+lane] = dP;
      __builtin_amdgcn_s_setprio(0);
    } else {
      // ============ WINDOW(t): hs(t+1) + dot partials for t+1 + zS(t+2) ============
      const int tn1 = (t+1)&3, tn2 = (t+2)&3;
      float xpre = 0.f;
      if (wave == 7 && lane < 7){
        const int tf = (t+3 < NS) ? t+3 : NS-1;
        xpre = xb[(size_t)tf*NIN + lane];
      }
      const float* Zsrc = ZS[(t+1)&1];
      float zi=Zsrc[lane], zf=Zsrc[64+lane], zg=Zsrc[128+lane], zo=Zsrc[192+lane];
      c_s = sigf(zf)*c_s + sigf(zi)*tanhf_(zg);
      float hsv = sigf(zo)*tanhf_(c_s);
      HSs[wave][lane] = hsv;
      const float4* H4 = (const float4*)HSs[wave];
      if (wave == 2 || wave >= 5){
        float a0=0.f,a1=0.f,s0=0.f,s1=0.f;
#pragma unroll
        for (int c=0;c<16;c++){
          float4 h = H4[c];
          FMAP(a0,a1,2*c,h); FMAP(s0,s1,52+2*c,h);
        }
        float4 xa=((const float4*)XL[tn1])[0], xb4=((const float4*)XL[tn1])[1];
        FMAP(a0,a1,32,xa); FMAP(a0,a1,34,xb4);
        zpart = a0+a1;
        float4 xc=((const float4*)XL[tn2])[0], xd=((const float4*)XL[tn2])[1];
        FMAP(s0,s1,84,xc); FMAP(s0,s1,86,xd);
        const int qoff = ((wave==2) ? 0 : (wave-4))*64;
        ZS[t&1][qoff+lane] = s0+s1;
      } else {
        float a0=0.f,a1=0.f;
#pragma unroll
        for (int c=0;c<16;c++){ float4 h = H4[c]; FMAP(a0,a1,2*c,h); }
        float4 xa=((const float4*)XL[tn1])[0], xb4=((const float4*)XL[tn1])[1];
        FMAP(a0,a1,32,xa); FMAP(a0,a1,34,xb4);
        zpart = a0+a1;
      }
      if (wave == 7 && lane < 7) XL[(t+3)&3][lane] = xpre;
    }
    __syncthreads();   // #2 : h(t), out done; next iteration may overwrite
  }
}

extern "C" void kernel_launch(void* const* d_in, const int* in_sizes, int n_in,
                              void* d_out, int out_size, void* d_ws, size_t ws_size,
                              hipStream_t stream) {
  (void)in_sizes; (void)n_in; (void)d_ws; (void)ws_size; (void)out_size;
  const float* X    = (const float*)d_in[0];
  const float* Wihs = (const float*)d_in[1];
  const float* Whhs = (const float*)d_in[2];
  const float* Bihs = (const float*)d_in[3];
  const float* Bhhs = (const float*)d_in[4];
  const float* Wiha = (const float*)d_in[5];
  const float* Whha = (const float*)d_in[6];
  const float* Biha = (const float*)d_in[7];
  const float* Bhha = (const float*)d_in[8];
  const float* Wihv = (const float*)d_in[9];
  const float* Whhv = (const float*)d_in[10];
  const float* Bihv = (const float*)d_in[11];
  const float* Bhhv = (const float*)d_in[12];
  const float* Wihp = (const float*)d_in[13];
  const float* Whhp = (const float*)d_in[14];
  const float* Bihp = (const float*)d_in[15];
  const float* Bhhp = (const float*)d_in[16];
  const float* Wa1  = (const float*)d_in[17];
  const float* Ba1  = (const float*)d_in[18];
  const float* Wa2  = (const float*)d_in[19];
  const float* Ba2  = (const float*)d_in[20];
  const float* Wv1  = (const float*)d_in[21];
  const float* Bv1  = (const float*)d_in[22];
  const float* Wv2  = (const float*)d_in[23];
  const float* Bv2  = (const float*)d_in[24];
  const float* Wp1  = (const float*)d_in[25];
  const float* Bp1  = (const float*)d_in[26];
  const float* Wp2  = (const float*)d_in[27];
  const float* Bp2  = (const float*)d_in[28];
  float* OUTP = (float*)d_out;

  mtinn_kernel<<<dim3(NB), dim3(512), 0, stream>>>(
      X, Wihs, Whhs, Bihs, Bhhs,
      Wiha, Whha, Biha, Bhha,
      Wihv, Whhv, Bihv, Bhhv,
      Wihp, Whhp, Bihp, Bhhp,
      Wa1, Ba1, Wa2, Ba2, Wv1, Bv1, Wv2, Bv2, Wp1, Bp1, Wp2, Bp2,
      OUTP);
}

// Round 8
// 4057.517 us; speedup vs baseline: 7.7043x; 1.1666x over previous
//
#include <hip/hip_runtime.h>

typedef unsigned int u32;

#define NIN 7
#define NB 256
#define NS 2048

__device__ __forceinline__ float fastrcp(float x){ return __builtin_amdgcn_rcpf(x); }
__device__ __forceinline__ float sigf(float x){ return fastrcp(1.f + __expf(-x)); }
__device__ __forceinline__ float tanhf_(float x){ return 1.f - 2.f*fastrcp(1.f + __expf(2.f*x)); }

__device__ __forceinline__ float blo(u32 u){ return __uint_as_float(u << 16); }
__device__ __forceinline__ float bhi(u32 u){ return __uint_as_float(u & 0xffff0000u); }
__device__ __forceinline__ u32 f2b(float f){            // RNE to bf16
  u32 x = __float_as_uint(f);
  return (x + 0x7fffu + ((x >> 16) & 1u)) >> 16;
}
__device__ __forceinline__ u32 pkb(float a, float b){ return f2b(a) | (f2b(b) << 16); }

template<int J>
__device__ __forceinline__ float rlf(float v){
  return __uint_as_float((unsigned)__builtin_amdgcn_readlane((int)__float_as_uint(v), J));
}
__device__ __forceinline__ float rlfv(float v, int j){   // j compile-time after unroll
  return __uint_as_float((unsigned)__builtin_amdgcn_readlane((int)__float_as_uint(v), j));
}

// identical gate math everywhere -> bit-identical c replicas across waves
__device__ __forceinline__ float gate4(float zi, float zf, float zg, float zo, float& c){
  c = sigf(zf)*c + sigf(zi)*tanhf_(zg);
  return sigf(zo)*tanhf_(c);
}

// acc pair += w[K],w[K+1] (4 bf16) dot float4 v
#define FMAP(a0, a1, K, v) { \
  u32 u0_ = w[(K)], u1_ = w[(K)+1]; \
  a0 = fmaf(blo(u0_), (v).x, a0); a1 = fmaf(bhi(u0_), (v).y, a1); \
  a0 = fmaf(blo(u1_), (v).z, a0); a1 = fmaf(bhi(u1_), (v).w, a1); }

// 32-elem dot, src broadcast via readlane (lanes 0..31), weights w[KB..KB+15]
#define DOTRL32(a0, a1, KB, src) { _Pragma("unroll") \
  for (int k_ = 0; k_ < 16; k_++){ \
    float s0_ = rlfv(src, 2*k_), s1_ = rlfv(src, 2*k_+1); \
    a0 = fmaf(blo(w[(KB)+k_]), s0_, a0); a1 = fmaf(bhi(w[(KB)+k_]), s1_, a1); } }

// 64-elem dot (lanes 0..63), weights w[KB..KB+31]
#define DOTRL64(a0, a1, KB, src) { _Pragma("unroll") \
  for (int k_ = 0; k_ < 32; k_++){ \
    float s0_ = rlfv(src, 2*k_), s1_ = rlfv(src, 2*k_+1); \
    a0 = fmaf(blo(w[(KB)+k_]), s0_, a0); a1 = fmaf(bhi(w[(KB)+k_]), s1_, a1); } }

// dual 64-elem dot sharing the readlane broadcasts (cell row + shared row)
#define DOTRL64x2(a0, a1, b0, b1, KA, KS, src) { _Pragma("unroll") \
  for (int k_ = 0; k_ < 32; k_++){ \
    float s0_ = rlfv(src, 2*k_), s1_ = rlfv(src, 2*k_+1); \
    a0 = fmaf(blo(w[(KA)+k_]), s0_, a0); a1 = fmaf(bhi(w[(KA)+k_]), s1_, a1); \
    b0 = fmaf(blo(w[(KS)+k_]), s0_, b0); b1 = fmaf(bhi(w[(KS)+k_]), s1_, b1); } }

// MLP: q=relu(b1 + W1 h) rows lane&15 (h from lanes 0..31), d=b2 + W2 q (q from lanes 0..15)
#define MLPP(hval, M1B, B1V, M2B, B2V, dres) { \
  float q0_ = (B1V), q1_ = 0.f; \
  _Pragma("unroll") \
  for (int j_ = 0; j_ < 16; j_++){ \
    u32 m_ = w[(M1B)+j_]; \
    q0_ = fmaf(blo(m_), rlfv(hval, 2*j_),   q0_); \
    q1_ = fmaf(bhi(m_), rlfv(hval, 2*j_+1), q1_); } \
  float qq_ = fmaxf(q0_+q1_, 0.f); \
  float e0_ = (B2V), e1_ = 0.f; \
  _Pragma("unroll") \
  for (int j_ = 0; j_ < 8; j_++){ \
    u32 m_ = w[(M2B)+j_]; \
    e0_ = fmaf(blo(m_), rlfv(qq_, 2*j_),   e0_); \
    e1_ = fmaf(bhi(m_), rlfv(qq_, 2*j_+1), e1_); } \
  dres = e0_ + e1_; }

__global__ __launch_bounds__(512, 1) void mtinn_kernel(
    const float* __restrict__ x,
    const float* wihs, const float* whhs, const float* bihs, const float* bhhs,
    const float* wiha, const float* whha, const float* biha, const float* bhha,
    const float* wihv, const float* whhv, const float* bihv, const float* bhhv,
    const float* wihp, const float* whhp, const float* bihp, const float* bhhp,
    const float* wa1, const float* ba1, const float* wa2, const float* ba2,
    const float* wv1, const float* bv1, const float* wv2, const float* bv2,
    const float* wp1, const float* bp1, const float* wp2, const float* bp2,
    float* __restrict__ out)
{
  __shared__ __align__(16) float ZS[2][256];     // shared-cell z, double buffered
  __shared__ __align__(16) float ZC[2][3][128];  // cell z (TAIL writes back d-adjusted vel/pos)
  __shared__ __align__(16) float ZP[64];         // att0 zpart handoff (w7 -> w4)
  __shared__ __align__(16) float XL[4][8];       // x ring; slot[7] = 1.0 (bias trick)

  const int tid  = threadIdx.x;
  const int wave = tid >> 6, lane = tid & 63, l = lane & 31;
  const int b    = blockIdx.x;
  const float* xb = x + (size_t)b * NS * NIN;

  // roles (wave -> SIMD is wave&3; balance per SIMD):
  // w0: A: x-prefetch issue        B: TAIL (+XL write)
  // w4: A: TOP-att0 (zpart<-ZP)    B: idle
  // w1: A: TOP-att1                B: WIN-att1 + sh-i
  // w5: A: TOP-vel0                B: WIN-vel0 + sh-g
  // w2: A: TOP-vel1                B: WIN-vel1 + sh-f
  // w6: A: TOP-pos0                B: WIN-pos0
  // w3: A: TOP-pos1                B: WIN-pos1
  // w7: A: idle                    B: WIN-att0 + sh-o (zpart->ZP)
  const bool isWin = (wave != 0 && wave != 4);
  const bool isSh  = (wave==1 || wave==2 || wave==5 || wave==7);
  const int  qoff  = (wave==1) ? 0 : (wave==2) ? 64 : (wave==5) ? 128 : 192;
  const bool isTop = (wave >= 1 && wave <= 6);
  const int  tc    = (wave==1||wave==4) ? 0 : (wave==2||wave==5) ? 1 : 2;
  const int  trb   = (wave >= 4) ? 0 : 64;
  const int  wc    = (wave==1||wave==7) ? 0 : (wave==2||wave==5) ? 1 : 2;
  const int  wrb   = (wave <= 3) ? 64 : 0;

  // ---- packed bf16 register weights, per-wave union (max ~91 u32) ----
  // cell waves: [0..15] hh | [16..47] hs | [48..51] x+bias | [52..83] sh-hs | [84..87] sh-x+bias
  // wave 0:     [0..15] m1a | [16..31] m1v | [32..47] m1p | [48..55] m2a | [56..63] m2v |
  //             [64..71] m2p | [72..79] velD | [80..87] posD | [88..90] biases (b1|b2)
  u32 w[92];
#pragma unroll
  for (int i = 0; i < 92; i++) w[i] = 0u;

  if (isWin){
    const float* wih = (wc==0) ? wiha : (wc==1) ? wihv : wihp;
    const float* bi  = (wc==0) ? biha : (wc==1) ? bihv : bihp;
    const float* bh  = (wc==0) ? bhha : (wc==1) ? bhhv : bhhp;
    const int L = (wc==0) ? 71 : (wc==1) ? 74 : 67;
    const int r = wrb + lane;
#pragma unroll
    for (int k=0;k<32;k++) w[16+k] = pkb(wih[r*L+2*k], wih[r*L+2*k+1]);
    const float bsum = bi[r] + bh[r];
    if (wc==0){
      w[48]=pkb(wih[r*L+64],wih[r*L+65]); w[49]=pkb(wih[r*L+66],wih[r*L+67]);
      w[50]=pkb(wih[r*L+68],wih[r*L+69]); w[51]=pkb(wih[r*L+70], bsum);
    } else if (wc==1){
      w[48]=pkb(wih[r*L+67],wih[r*L+68]); w[49]=pkb(wih[r*L+69],wih[r*L+70]);
      w[50]=pkb(wih[r*L+71],wih[r*L+72]); w[51]=pkb(wih[r*L+73], bsum);
    } else {
      w[51]=pkb(0.f, bsum);                     // pos: no x-weights
    }
  }
  if (isTop){
    const float* whh = (tc==0) ? whha : (tc==1) ? whhv : whhp;
    const int r = trb + lane;
#pragma unroll
    for (int k=0;k<16;k++) w[k] = pkb(whh[r*32+2*k], whh[r*32+2*k+1]);
  }
  if (isSh){
    const int r = qoff + lane;
#pragma unroll
    for (int k=0;k<32;k++) w[52+k] = pkb(whhs[r*64+2*k], whhs[r*64+2*k+1]);
    w[84]=pkb(wihs[r*7+0],wihs[r*7+1]); w[85]=pkb(wihs[r*7+2],wihs[r*7+3]);
    w[86]=pkb(wihs[r*7+4],wihs[r*7+5]); w[87]=pkb(wihs[r*7+6], bihs[r]+bhhs[r]);
  }
  if (wave == 0){
    const int mi = lane & 15, mm = lane % 3;
#pragma unroll
    for (int k=0;k<16;k++){
      w[k]    = pkb(wa1[mi*32+2*k], wa1[mi*32+2*k+1]);
      w[16+k] = pkb(wv1[mi*32+2*k], wv1[mi*32+2*k+1]);
      w[32+k] = pkb(wp1[mi*32+2*k], wp1[mi*32+2*k+1]);
    }
#pragma unroll
    for (int k=0;k<8;k++){
      w[48+k] = pkb(wa2[mm*16+2*k], wa2[mm*16+2*k+1]);
      w[56+k] = pkb(wv2[mm*16+2*k], wv2[mm*16+2*k+1]);
      w[64+k] = pkb(wp2[mm*16+2*k], wp2[mm*16+2*k+1]);
    }
#pragma unroll
    for (int g=0; g<4; g++){
      int rr = g*32 + l;
      w[72+2*g]   = pkb(wihv[rr*74+64], wihv[rr*74+65]);
      w[72+2*g+1] = pkb(wihv[rr*74+66], 0.f);
      w[80+2*g]   = pkb(wihp[rr*67+64], wihp[rr*67+65]);
      w[80+2*g+1] = pkb(wihp[rr*67+66], 0.f);
    }
    w[88]=pkb(ba1[mi], ba2[mm]); w[89]=pkb(bv1[mi], bv2[mm]); w[90]=pkb(bp1[mi], bp2[mm]);
  }

  // ---- LDS init + priming ----
  if (tid < 8){
    XL[0][tid] = (tid<7) ? xb[tid]         : 1.f;
    XL[1][tid] = (tid<7) ? xb[NIN+tid]     : 1.f;
    XL[2][tid] = (tid<7) ? xb[2*NIN+tid]   : 1.f;
    XL[3][tid] = 1.f;
  }
  if (tid < 384){                                    // prime ZC["t=-1"]: f,o gates = -40 -> h=0, c=0
    int cell = tid >> 7, r = tid & 127;
    ZC[1][cell][r] = ((r >> 5) & 1) ? -40.f : 0.f;
  }
  __syncthreads();

  // ---- prologue: zS(0) ----
  if (isSh){
    const float4* X0 = (const float4*)XL[0];
    float4 xa = X0[0], xb4 = X0[1];
    float s0=0.f, s1=0.f; FMAP(s0,s1,84,xa); FMAP(s0,s1,86,xb4);
    ZS[0][qoff + lane] = s0 + s1;
  }
  __syncthreads();

  float c_s = 0.f, crep = 0.f;
  float c_a = 0.f, c_v = 0.f, c_p = 0.f;   // wave 0
  float zpart = 0.f;

  // ---- prologue: hs(0), zpart(0), zS(1) ----
  if (isWin){
    float zi_=ZS[0][lane], zf_=ZS[0][64+lane], zg_=ZS[0][128+lane], zo_=ZS[0][192+lane];
    float hsv = gate4(zi_,zf_,zg_,zo_, c_s);
    const float4* X0 = (const float4*)XL[0];
    float4 xa = X0[0], xb4 = X0[1];
    float a0=0.f, a1=0.f; FMAP(a0,a1,48,xa); FMAP(a0,a1,50,xb4);
    if (isSh){
      const float4* X1 = (const float4*)XL[1];
      float4 xc = X1[0], xd = X1[1];
      float s0=0.f, s1=0.f; FMAP(s0,s1,84,xc); FMAP(s0,s1,86,xd);
      DOTRL64x2(a0,a1,s0,s1,16,52,hsv);
      ZS[1][qoff + lane] = s0 + s1;
    } else {
      DOTRL64(a0,a1,16,hsv);
    }
    zpart = a0 + a1;
    if (wave == 7) ZP[lane] = zpart;
  }
  __syncthreads();

  // ================= pipelined recurrence =================
#pragma unroll 1
  for (int t = 0; t < NS; t++){
    float xpre = 0.f;
    // ---- PHASE A: TOP (recompute h(t-1) from adjusted z, finish z(t)) ----
    if (wave == 0){
      if (lane < 7){
        const int tf = (t+3 < NS) ? t+3 : NS-1;
        xpre = xb[(size_t)tf*NIN + lane];
      }
    } else if (isTop){
      const float* zc = ZC[(t^1)&1][tc];
      float zi_=zc[l], zf_=zc[32+l], zg_=zc[64+l], zo_=zc[96+l];
      float h = gate4(zi_,zf_,zg_,zo_, crep);
      float z0 = (wave == 4) ? ZP[lane] : zpart;
      float z1 = 0.f;
      DOTRL32(z0,z1,0,h);
      ZC[t&1][tc][trb + lane] = z0 + z1;
    }
    __syncthreads();   // #1

    // ---- PHASE B ----
    if (wave == 0){
      // ================= TAIL =================
      __builtin_amdgcn_s_setprio(1);
      const float* zca = ZC[t&1][0];
      const float* zcv = ZC[t&1][1];
      const float* zcp = ZC[t&1][2];
      float zai=zca[l], zaf=zca[32+l], zag=zca[64+l], zao=zca[96+l];
      float zvi=zcv[l], zvf=zcv[32+l], zvg=zcv[64+l], zvo=zcv[96+l];
      float zpi=zcp[l], zpf=zcp[32+l], zpg=zcp[64+l], zpo=zcp[96+l];
      float* ob = out + ((size_t)b*NS + t)*9;
      // ATT
      float ha = gate4(zai,zaf,zag,zao, c_a);
      float dA; MLPP(ha, 0, blo(w[88]), 48, bhi(w[88]), dA);
      if (lane < 3) ob[lane] = dA;
      float dx=rlf<0>(dA), dy=rlf<1>(dA), dz=rlf<2>(dA);
      // VEL (+ d_att columns, write adjusted z back for TOP's recompute)
      zvi = fmaf(blo(w[72]),dx, fmaf(bhi(w[72]),dy, fmaf(blo(w[73]),dz, zvi)));
      zvf = fmaf(blo(w[74]),dx, fmaf(bhi(w[74]),dy, fmaf(blo(w[75]),dz, zvf)));
      zvg = fmaf(blo(w[76]),dx, fmaf(bhi(w[76]),dy, fmaf(blo(w[77]),dz, zvg)));
      zvo = fmaf(blo(w[78]),dx, fmaf(bhi(w[78]),dy, fmaf(blo(w[79]),dz, zvo)));
      if (lane < 32){ float* zw = ZC[t&1][1]; zw[l]=zvi; zw[32+l]=zvf; zw[64+l]=zvg; zw[96+l]=zvo; }
      float hv = gate4(zvi,zvf,zvg,zvo, c_v);
      float dV; MLPP(hv, 16, blo(w[89]), 56, bhi(w[89]), dV);
      if (lane < 3) ob[3+lane] = dV;
      dx=rlf<0>(dV); dy=rlf<1>(dV); dz=rlf<2>(dV);
      // POS (+ d_vel columns)
      zpi = fmaf(blo(w[80]),dx, fmaf(bhi(w[80]),dy, fmaf(blo(w[81]),dz, zpi)));
      zpf = fmaf(blo(w[82]),dx, fmaf(bhi(w[82]),dy, fmaf(blo(w[83]),dz, zpf)));
      zpg = fmaf(blo(w[84]),dx, fmaf(bhi(w[84]),dy, fmaf(blo(w[85]),dz, zpg)));
      zpo = fmaf(blo(w[86]),dx, fmaf(bhi(w[86]),dy, fmaf(blo(w[87]),dz, zpo)));
      if (lane < 32){ float* zw = ZC[t&1][2]; zw[l]=zpi; zw[32+l]=zpf; zw[64+l]=zpg; zw[96+l]=zpo; }
      float hp_ = gate4(zpi,zpf,zpg,zpo, c_p);
      float dP; MLPP(hp_, 32, blo(w[90]), 64, bhi(w[90]), dP);
      if (lane < 3) ob[6+lane] = dP;
      __builtin_amdgcn_s_setprio(0);
      if (lane < 7) XL[(t+3)&3][lane] = xpre;          // prefetch landed; consumed next iter
    } else if (isWin){
      // ============ WINDOW: hs(t+1), zpart(t+1), zS(t+2) ============
      const float* Zsrc = ZS[(t+1)&1];
      float zi_=Zsrc[lane], zf_=Zsrc[64+lane], zg_=Zsrc[128+lane], zo_=Zsrc[192+lane];
      float hsv = gate4(zi_,zf_,zg_,zo_, c_s);
      const float4* X1 = (const float4*)XL[(t+1)&3];
      float4 xa = X1[0], xb4 = X1[1];
      float a0=0.f, a1=0.f; FMAP(a0,a1,48,xa); FMAP(a0,a1,50,xb4);
      if (isSh){
        const float4* X2 = (const float4*)XL[(t+2)&3];
        float4 xc = X2[0], xd = X2[1];
        float s0=0.f, s1=0.f; FMAP(s0,s1,84,xc); FMAP(s0,s1,86,xd);
        DOTRL64x2(a0,a1,s0,s1,16,52,hsv);
        ZS[t&1][qoff + lane] = s0 + s1;
      } else {
        DOTRL64(a0,a1,16,hsv);
      }
      zpart = a0 + a1;
      if (wave == 7) ZP[lane] = zpart;
    }
    __syncthreads();   // #2
  }
}

extern "C" void kernel_launch(void* const* d_in, const int* in_sizes, int n_in,
                              void* d_out, int out_size, void* d_ws, size_t ws_size,
                              hipStream_t stream) {
  (void)in_sizes; (void)n_in; (void)d_ws; (void)ws_size; (void)out_size;
  const float* X    = (const float*)d_in[0];
  const float* Wihs = (const float*)d_in[1];
  const float* Whhs = (const float*)d_in[2];
  const float* Bihs = (const float*)d_in[3];
  const float* Bhhs = (const float*)d_in[4];
  const float* Wiha = (const float*)d_in[5];
  const float* Whha = (const float*)d_in[6];
  const float* Biha = (const float*)d_in[7];
  const float* Bhha = (const float*)d_in[8];
  const float* Wihv = (const float*)d_in[9];
  const float* Whhv = (const float*)d_in[10];
  const float* Bihv = (const float*)d_in[11];
  const float* Bhhv = (const float*)d_in[12];
  const float* Wihp = (const float*)d_in[13];
  const float* Whhp = (const float*)d_in[14];
  const float* Bihp = (const float*)d_in[15];
  const float* Bhhp = (const float*)d_in[16];
  const float* Wa1  = (const float*)d_in[17];
  const float* Ba1  = (const float*)d_in[18];
  const float* Wa2  = (const float*)d_in[19];
  const float* Ba2  = (const float*)d_in[20];
  const float* Wv1  = (const float*)d_in[21];
  const float* Bv1  = (const float*)d_in[22];
  const float* Wv2  = (const float*)d_in[23];
  const float* Bv2  = (const float*)d_in[24];
  const float* Wp1  = (const float*)d_in[25];
  const float* Bp1  = (const float*)d_in[26];
  const float* Wp2  = (const float*)d_in[27];
  const float* Bp2  = (const float*)d_in[28];
  float* OUTP = (float*)d_out;

  mtinn_kernel<<<dim3(NB), dim3(512), 0, stream>>>(
      X, Wihs, Whhs, Bihs, Bhhs,
      Wiha, Whha, Biha, Bhha,
      Wihv, Whhv, Bihv, Bhhv,
      Wihp, Whhp, Bihp, Bhhp,
      Wa1, Ba1, Wa2, Ba2, Wv1, Bv1, Wv2, Bv2, Wp1, Bp1, Wp2, Bp2,
      OUTP);
}

// Round 10
// 3178.056 us; speedup vs baseline: 9.8363x; 1.2767x over previous
//
#include <hip/hip_runtime.h>

typedef unsigned int u32;

#define NIN 7
#define NB 256
#define NS 2048

__device__ __forceinline__ float fastrcp(float x){ return __builtin_amdgcn_rcpf(x); }
__device__ __forceinline__ float sigf(float x){ return fastrcp(1.f + __expf(-x)); }
__device__ __forceinline__ float tanhf_(float x){ return 1.f - 2.f*fastrcp(1.f + __expf(2.f*x)); }

// RNE f16 pack (v_cvt_f16_f32 is RNE; activations stay f32 everywhere)
__device__ __forceinline__ u32 pkh(float a, float b){
  unsigned short ua = __builtin_bit_cast(unsigned short, (_Float16)a);
  unsigned short ub = __builtin_bit_cast(unsigned short, (_Float16)b);
  return (u32)ua | ((u32)ub << 16);
}

template<int J>
__device__ __forceinline__ float rlf(float v){
  return __uint_as_float((unsigned)__builtin_amdgcn_readlane((int)__float_as_uint(v), J));
}
__device__ __forceinline__ float rlfv(float v, int j){   // j compile-time after unroll
  return __uint_as_float((unsigned)__builtin_amdgcn_readlane((int)__float_as_uint(v), j));
}

// acc += f16(lo/hi of wp) * act(f32) + acc, f32 accumulate. act broadcast via SGPR.
__device__ __forceinline__ float mxl(float acc, u32 wp, float a){
  asm("v_fma_mix_f32 %0, %1, %2, %3 op_sel_hi:[1,0,0]"
      : "=v"(acc) : "v"(wp), "s"(a), "0"(acc));
  return acc;
}
__device__ __forceinline__ float mxh(float acc, u32 wp, float a){
  asm("v_fma_mix_f32 %0, %1, %2, %3 op_sel:[1,0,0] op_sel_hi:[1,0,0]"
      : "=v"(acc) : "v"(wp), "s"(a), "0"(acc));
  return acc;
}
// VGPR-act variants (x vectors from LDS)
__device__ __forceinline__ float mxlv(float acc, u32 wp, float a){
  asm("v_fma_mix_f32 %0, %1, %2, %3 op_sel_hi:[1,0,0]"
      : "=v"(acc) : "v"(wp), "v"(a), "0"(acc));
  return acc;
}
__device__ __forceinline__ float mxhv(float acc, u32 wp, float a){
  asm("v_fma_mix_f32 %0, %1, %2, %3 op_sel:[1,0,0] op_sel_hi:[1,0,0]"
      : "=v"(acc) : "v"(wp), "v"(a), "0"(acc));
  return acc;
}

// identical gate math everywhere -> bit-identical c replicas across waves
__device__ __forceinline__ float gate4(float zi, float zf, float zg, float zo, float& c){
  c = sigf(zf)*c + sigf(zi)*tanhf_(zg);
  return sigf(zo)*tanhf_(c);
}

// 8-elem x+bias dot: w[KB..KB+3] (8 f16) . {v0,v1}
#define XD(a0, a1, KB, v0, v1) { \
  a0 = mxlv(a0, w[(KB)+0], (v0).x); a1 = mxhv(a1, w[(KB)+0], (v0).y); \
  a0 = mxlv(a0, w[(KB)+1], (v0).z); a1 = mxhv(a1, w[(KB)+1], (v0).w); \
  a0 = mxlv(a0, w[(KB)+2], (v1).x); a1 = mxhv(a1, w[(KB)+2], (v1).y); \
  a0 = mxlv(a0, w[(KB)+3], (v1).z); a1 = mxhv(a1, w[(KB)+3], (v1).w); }

// 64-elem dual-row dot (cell row + shared row share f32 broadcasts)
#define MX2(a0, a1, s0, s1, KA, KS, SRC) { _Pragma("unroll") \
  for (int k_ = 0; k_ < 32; k_++){ \
    float e0_ = rlfv(SRC, 2*k_), e1_ = rlfv(SRC, 2*k_+1); \
    a0 = mxl(a0, w[(KA)+k_], e0_); a1 = mxh(a1, w[(KA)+k_], e1_); \
    s0 = mxl(s0, w[(KS)+k_], e0_); s1 = mxh(s1, w[(KS)+k_], e1_); } }

// 64-elem single-row dot
#define MX1(a0, a1, KA, SRC) { _Pragma("unroll") \
  for (int k_ = 0; k_ < 32; k_++){ \
    float e0_ = rlfv(SRC, 2*k_), e1_ = rlfv(SRC, 2*k_+1); \
    a0 = mxl(a0, w[(KA)+k_], e0_); a1 = mxh(a1, w[(KA)+k_], e1_); } }

// 32-elem dot (hh)
#define MXH16(z0, z1, KB, SRC) { _Pragma("unroll") \
  for (int k_ = 0; k_ < 16; k_++){ \
    float e0_ = rlfv(SRC, 2*k_), e1_ = rlfv(SRC, 2*k_+1); \
    z0 = mxl(z0, w[(KB)+k_], e0_); z1 = mxh(z1, w[(KB)+k_], e1_); } }

// MLP: q=relu(b1+W1 h) rows lane&15 (h f32 from lanes 0..31), d=b2+W2 q (q from lanes 0..15)
#define MLPX(HS, M1B, B1V, M2B, B2V, dres) { \
  float q0_ = (B1V), q1_ = 0.f; \
  _Pragma("unroll") \
  for (int j_ = 0; j_ < 16; j_++){ \
    float e0_ = rlfv(HS, 2*j_), e1_ = rlfv(HS, 2*j_+1); \
    q0_ = mxl(q0_, w[(M1B)+j_], e0_); q1_ = mxh(q1_, w[(M1B)+j_], e1_); } \
  float qq_ = fmaxf(q0_+q1_, 0.f); \
  float f0_ = (B2V), f1_ = 0.f; \
  _Pragma("unroll") \
  for (int j_ = 0; j_ < 8; j_++){ \
    float e0_ = rlfv(qq_, 2*j_), e1_ = rlfv(qq_, 2*j_+1); \
    f0_ = mxl(f0_, w[(M2B)+j_], e0_); f1_ = mxh(f1_, w[(M2B)+j_], e1_); } \
  dres = f0_ + f1_; }

__global__ __launch_bounds__(512, 1) void mtinn_kernel(
    const float* __restrict__ x,
    const float* wihs, const float* whhs, const float* bihs, const float* bhhs,
    const float* wiha, const float* whha, const float* biha, const float* bhha,
    const float* wihv, const float* whhv, const float* bihv, const float* bhhv,
    const float* wihp, const float* whhp, const float* bihp, const float* bhhp,
    const float* wa1, const float* ba1, const float* wa2, const float* ba2,
    const float* wv1, const float* bv1, const float* wv2, const float* bv2,
    const float* wp1, const float* bp1, const float* wp2, const float* bp2,
    float* __restrict__ out)
{
  __shared__ __align__(16) float ZS[2][256];     // shared-cell z, double buffered
  __shared__ __align__(16) float ZC[2][3][128];  // cell z (TAIL writes back d-adjusted vel/pos)
  __shared__ __align__(16) float ZP[64];         // att0 zpart handoff (w7 -> w4)
  __shared__ __align__(16) float XL[4][8];       // x ring; slot[7] = 1.0 (bias trick)

  const int tid  = threadIdx.x;
  const int wave = tid >> 6, lane = tid & 63, l = lane & 31;
  const int b    = blockIdx.x;
  const float* xb = x + (size_t)b * NS * NIN;

  // roles (wave -> SIMD is wave&3):
  // w0: A: x-prefetch issue        B: TAIL (+XL write)
  // w4: A: TOP-att0 (zpart<-ZP)    B: idle
  // w1: A: TOP-att1                B: WIN-att1 + sh-i
  // w5: A: TOP-vel0                B: WIN-vel0 + sh-g
  // w2: A: TOP-vel1                B: WIN-vel1 + sh-f
  // w6: A: TOP-pos0                B: WIN-pos0
  // w3: A: TOP-pos1                B: WIN-pos1
  // w7: A: idle                    B: WIN-att0 + sh-o (zpart->ZP)
  const bool isWin = (wave != 0 && wave != 4);
  const bool isSh  = (wave==1 || wave==2 || wave==5 || wave==7);
  const int  qoff  = (wave==1) ? 0 : (wave==2) ? 64 : (wave==5) ? 128 : 192;
  const bool isTop = (wave >= 1 && wave <= 6);
  const int  tc    = (wave==1||wave==4) ? 0 : (wave==2||wave==5) ? 1 : 2;
  const int  trb   = (wave >= 4) ? 0 : 64;
  const int  wc    = (wave==1||wave==7) ? 0 : (wave==2||wave==5) ? 1 : 2;
  const int  wrb   = (wave <= 3) ? 64 : 0;

  // ---- packed f16 register weights, per-wave union ----
  // cell waves: [0..15] hh | [16..47] hs | [48..51] x+bias | [52..83] sh-hs | [84..87] sh-x+bias
  // wave 0:     [0..15] m1a | [16..31] m1v | [32..47] m1p | [48..55] m2a | [56..63] m2v |
  //             [64..71] m2p | [72..79] velD | [80..87] posD
  u32 w[88];
#pragma unroll
  for (int i = 0; i < 88; i++) w[i] = 0u;
  float b1a=0.f,b1v=0.f,b1p=0.f,b2a=0.f,b2v=0.f,b2p=0.f;   // wave 0 MLP biases (f32)

  if (isWin){
    const float* wih = (wc==0) ? wiha : (wc==1) ? wihv : wihp;
    const float* bi  = (wc==0) ? biha : (wc==1) ? bihv : bihp;
    const float* bh  = (wc==0) ? bhha : (wc==1) ? bhhv : bhhp;
    const int L = (wc==0) ? 71 : (wc==1) ? 74 : 67;
    const int r = wrb + lane;
#pragma unroll
    for (int k=0;k<32;k++) w[16+k] = pkh(wih[r*L+2*k], wih[r*L+2*k+1]);
    const float bsum = bi[r] + bh[r];
    if (wc==0){
      w[48]=pkh(wih[r*L+64],wih[r*L+65]); w[49]=pkh(wih[r*L+66],wih[r*L+67]);
      w[50]=pkh(wih[r*L+68],wih[r*L+69]); w[51]=pkh(wih[r*L+70], bsum);
    } else if (wc==1){
      w[48]=pkh(wih[r*L+67],wih[r*L+68]); w[49]=pkh(wih[r*L+69],wih[r*L+70]);
      w[50]=pkh(wih[r*L+71],wih[r*L+72]); w[51]=pkh(wih[r*L+73], bsum);
    } else {
      w[51]=pkh(0.f, bsum);                     // pos: no x-weights
    }
  }
  if (isTop){
    const float* whh = (tc==0) ? whha : (tc==1) ? whhv : whhp;
    const int r = trb + lane;
#pragma unroll
    for (int k=0;k<16;k++) w[k] = pkh(whh[r*32+2*k], whh[r*32+2*k+1]);
  }
  if (isSh){
    const int r = qoff + lane;
#pragma unroll
    for (int k=0;k<32;k++) w[52+k] = pkh(whhs[r*64+2*k], whhs[r*64+2*k+1]);
    w[84]=pkh(wihs[r*7+0],wihs[r*7+1]); w[85]=pkh(wihs[r*7+2],wihs[r*7+3]);
    w[86]=pkh(wihs[r*7+4],wihs[r*7+5]); w[87]=pkh(wihs[r*7+6], bihs[r]+bhhs[r]);
  }
  if (wave == 0){
    const int mi = lane & 15, mm = lane % 3;
#pragma unroll
    for (int k=0;k<16;k++){
      w[k]    = pkh(wa1[mi*32+2*k], wa1[mi*32+2*k+1]);
      w[16+k] = pkh(wv1[mi*32+2*k], wv1[mi*32+2*k+1]);
      w[32+k] = pkh(wp1[mi*32+2*k], wp1[mi*32+2*k+1]);
    }
#pragma unroll
    for (int k=0;k<8;k++){
      w[48+k] = pkh(wa2[mm*16+2*k], wa2[mm*16+2*k+1]);
      w[56+k] = pkh(wv2[mm*16+2*k], wv2[mm*16+2*k+1]);
      w[64+k] = pkh(wp2[mm*16+2*k], wp2[mm*16+2*k+1]);
    }
#pragma unroll
    for (int g=0; g<4; g++){
      int rr = g*32 + l;
      w[72+2*g]   = pkh(wihv[rr*74+64], wihv[rr*74+65]);
      w[72+2*g+1] = pkh(wihv[rr*74+66], 0.f);
      w[80+2*g]   = pkh(wihp[rr*67+64], wihp[rr*67+65]);
      w[80+2*g+1] = pkh(wihp[rr*67+66], 0.f);
    }
    b1a=ba1[mi]; b1v=bv1[mi]; b1p=bp1[mi];
    b2a=ba2[mm]; b2v=bv2[mm]; b2p=bp2[mm];
  }

  // ---- LDS init + priming ----
  if (tid < 8){
    XL[0][tid] = (tid<7) ? xb[tid]         : 1.f;
    XL[1][tid] = (tid<7) ? xb[NIN+tid]     : 1.f;
    XL[2][tid] = (tid<7) ? xb[2*NIN+tid]   : 1.f;
    XL[3][tid] = 1.f;
  }
  if (tid < 384){                                    // prime ZC["t=-1"]: f,o gates = -40 -> h=0, c=0
    int cell = tid >> 7, r = tid & 127;
    ZC[1][cell][r] = ((r >> 5) & 1) ? -40.f : 0.f;
  }
  __syncthreads();

  // ---- prologue: zS(0) ----
  if (isSh){
    const float4* X0 = (const float4*)XL[0];
    float4 xa = X0[0], xb4 = X0[1];
    float s0=0.f, s1=0.f; XD(s0,s1,84,xa,xb4);
    ZS[0][qoff + lane] = s0 + s1;
  }
  __syncthreads();

  float c_s = 0.f, crep = 0.f;
  float c_a = 0.f, c_v = 0.f, c_p = 0.f;   // wave 0
  float zpart = 0.f;

  // ---- prologue: hs(0), zpart(0), zS(1) ----
  if (isWin){
    float zi_=ZS[0][lane], zf_=ZS[0][64+lane], zg_=ZS[0][128+lane], zo_=ZS[0][192+lane];
    float hsv = gate4(zi_,zf_,zg_,zo_, c_s);
    const float4* X0 = (const float4*)XL[0];
    float4 xa = X0[0], xb4 = X0[1];
    float a0=0.f, a1=0.f; XD(a0,a1,48,xa,xb4);
    if (isSh){
      const float4* X1 = (const float4*)XL[1];
      float4 xc = X1[0], xd = X1[1];
      float s0=0.f, s1=0.f; XD(s0,s1,84,xc,xd);
      MX2(a0,a1,s0,s1,16,52,hsv);
      ZS[1][qoff + lane] = s0 + s1;
    } else {
      MX1(a0,a1,16,hsv);
    }
    zpart = a0 + a1;
    if (wave == 7) ZP[lane] = zpart;
  }
  __syncthreads();

  // ================= pipelined recurrence =================
#pragma unroll 1
  for (int t = 0; t < NS; t++){
    float xpre = 0.f;
    // ---- PHASE A: TOP (recompute h(t-1) from adjusted z, finish z(t)) ----
    if (wave == 0){
      if (lane < 7){
        const int tf = (t+3 < NS) ? t+3 : NS-1;
        xpre = xb[(size_t)tf*NIN + lane];
      }
    } else if (isTop){
      const float* zc = ZC[(t^1)&1][tc];
      float zi_=zc[l], zf_=zc[32+l], zg_=zc[64+l], zo_=zc[96+l];
      float h = gate4(zi_,zf_,zg_,zo_, crep);
      float z0 = (wave == 4) ? ZP[lane] : zpart;
      float z1 = 0.f;
      MXH16(z0,z1,0,h);
      ZC[t&1][tc][trb + lane] = z0 + z1;
    }
    __syncthreads();   // #1

    // ---- PHASE B ----
    if (wave == 0){
      // ================= TAIL =================
      __builtin_amdgcn_s_setprio(1);
      const float* zca = ZC[t&1][0];
      const float* zcv = ZC[t&1][1];
      const float* zcp = ZC[t&1][2];
      float zai=zca[l], zaf=zca[32+l], zag=zca[64+l], zao=zca[96+l];
      float zvi=zcv[l], zvf=zcv[32+l], zvg=zcv[64+l], zvo=zcv[96+l];
      float zpi=zcp[l], zpf=zcp[32+l], zpg=zcp[64+l], zpo=zcp[96+l];
      float* ob = out + ((size_t)b*NS + t)*9;
      // ATT
      float ha = gate4(zai,zaf,zag,zao, c_a);
      float dA; MLPX(ha, 0, b1a, 48, b2a, dA);
      if (lane < 3) ob[lane] = dA;
      float dx=rlf<0>(dA), dy=rlf<1>(dA), dz=rlf<2>(dA);
      // VEL (+ d_att columns, write adjusted z back for TOP's recompute)
      zvi = mxl(zvi, w[72], dx); zvi = mxh(zvi, w[72], dy); zvi = mxl(zvi, w[73], dz);
      zvf = mxl(zvf, w[74], dx); zvf = mxh(zvf, w[74], dy); zvf = mxl(zvf, w[75], dz);
      zvg = mxl(zvg, w[76], dx); zvg = mxh(zvg, w[76], dy); zvg = mxl(zvg, w[77], dz);
      zvo = mxl(zvo, w[78], dx); zvo = mxh(zvo, w[78], dy); zvo = mxl(zvo, w[79], dz);
      if (lane < 32){ float* zw = ZC[t&1][1]; zw[l]=zvi; zw[32+l]=zvf; zw[64+l]=zvg; zw[96+l]=zvo; }
      float hv = gate4(zvi,zvf,zvg,zvo, c_v);
      float dV; MLPX(hv, 16, b1v, 56, b2v, dV);
      if (lane < 3) ob[3+lane] = dV;
      dx=rlf<0>(dV); dy=rlf<1>(dV); dz=rlf<2>(dV);
      // POS (+ d_vel columns)
      zpi = mxl(zpi, w[80], dx); zpi = mxh(zpi, w[80], dy); zpi = mxl(zpi, w[81], dz);
      zpf = mxl(zpf, w[82], dx); zpf = mxh(zpf, w[82], dy); zpf = mxl(zpf, w[83], dz);
      zpg = mxl(zpg, w[84], dx); zpg = mxh(zpg, w[84], dy); zpg = mxl(zpg, w[85], dz);
      zpo = mxl(zpo, w[86], dx); zpo = mxh(zpo, w[86], dy); zpo = mxl(zpo, w[87], dz);
      if (lane < 32){ float* zw = ZC[t&1][2]; zw[l]=zpi; zw[32+l]=zpf; zw[64+l]=zpg; zw[96+l]=zpo; }
      float hp_ = gate4(zpi,zpf,zpg,zpo, c_p);
      float dP; MLPX(hp_, 32, b1p, 64, b2p, dP);
      if (lane < 3) ob[6+lane] = dP;
      __builtin_amdgcn_s_setprio(0);
      if (lane < 7) XL[(t+3)&3][lane] = xpre;          // prefetch landed; consumed next iter
    } else if (isWin){
      // ============ WINDOW: hs(t+1), zpart(t+1), zS(t+2) ============
      const float* Zsrc = ZS[(t+1)&1];
      float zi_=Zsrc[lane], zf_=Zsrc[64+lane], zg_=Zsrc[128+lane], zo_=Zsrc[192+lane];
      float hsv = gate4(zi_,zf_,zg_,zo_, c_s);
      const float4* X1 = (const float4*)XL[(t+1)&3];
      float4 xa = X1[0], xb4 = X1[1];
      float a0=0.f, a1=0.f; XD(a0,a1,48,xa,xb4);
      if (isSh){
        const float4* X2 = (const float4*)XL[(t+2)&3];
        float4 xc = X2[0], xd = X2[1];
        float s0=0.f, s1=0.f; XD(s0,s1,84,xc,xd);
        MX2(a0,a1,s0,s1,16,52,hsv);
        ZS[t&1][qoff + lane] = s0 + s1;
      } else {
        MX1(a0,a1,16,hsv);
      }
      zpart = a0 + a1;
      if (wave == 7) ZP[lane] = zpart;
    }
    __syncthreads();   // #2
  }
}

extern "C" void kernel_launch(void* const* d_in, const int* in_sizes, int n_in,
                              void* d_out, int out_size, void* d_ws, size_t ws_size,
                              hipStream_t stream) {
  (void)in_sizes; (void)n_in; (void)d_ws; (void)ws_size; (void)out_size;
  const float* X    = (const float*)d_in[0];
  const float* Wihs = (const float*)d_in[1];
  const float* Whhs = (const float*)d_in[2];
  const float* Bihs = (const float*)d_in[3];
  const float* Bhhs = (const float*)d_in[4];
  const float* Wiha = (const float*)d_in[5];
  const float* Whha = (const float*)d_in[6];
  const float* Biha = (const float*)d_in[7];
  const float* Bhha = (const float*)d_in[8];
  const float* Wihv = (const float*)d_in[9];
  const float* Whhv = (const float*)d_in[10];
  const float* Bihv = (const float*)d_in[11];
  const float* Bhhv = (const float*)d_in[12];
  const float* Wihp = (const float*)d_in[13];
  const float* Whhp = (const float*)d_in[14];
  const float* Bihp = (const float*)d_in[15];
  const float* Bhhp = (const float*)d_in[16];
  const float* Wa1  = (const float*)d_in[17];
  const float* Ba1  = (const float*)d_in[18];
  const float* Wa2  = (const float*)d_in[19];
  const float* Ba2  = (const float*)d_in[20];
  const float* Wv1  = (const float*)d_in[21];
  const float* Bv1  = (const float*)d_in[22];
  const float* Wv2  = (const float*)d_in[23];
  const float* Bv2  = (const float*)d_in[24];
  const float* Wp1  = (const float*)d_in[25];
  const float* Bp1  = (const float*)d_in[26];
  const float* Wp2  = (const float*)d_in[27];
  const float* Bp2  = (const float*)d_in[28];
  float* OUTP = (float*)d_out;

  mtinn_kernel<<<dim3(NB), dim3(512), 0, stream>>>(
      X, Wihs, Whhs, Bihs, Bhhs,
      Wiha, Whha, Biha, Bhha,
      Wihv, Whhv, Bihv, Bhhv,
      Wihp, Whhp, Bihp, Bhhp,
      Wa1, Ba1, Wa2, Ba2, Wv1, Bv1, Wv2, Bv2, Wp1, Bp1, Wp2, Bp2,
      OUTP);
}

// Round 11
// 2871.365 us; speedup vs baseline: 10.8869x; 1.1068x over previous
//
#include <hip/hip_runtime.h>

typedef unsigned int u32;

#define NIN 7
#define NB 256
#define NS 2048

__device__ __forceinline__ float fastrcp(float x){ return __builtin_amdgcn_rcpf(x); }
__device__ __forceinline__ float sigf(float x){ return fastrcp(1.f + __expf(-x)); }
__device__ __forceinline__ float tanhf_(float x){ return 1.f - 2.f*fastrcp(1.f + __expf(2.f*x)); }

// RNE f16 pack (v_cvt_f16_f32 is RNE; activations stay f32 everywhere)
__device__ __forceinline__ u32 pkh(float a, float b){
  unsigned short ua = __builtin_bit_cast(unsigned short, (_Float16)a);
  unsigned short ub = __builtin_bit_cast(unsigned short, (_Float16)b);
  return (u32)ua | ((u32)ub << 16);
}

template<int J>
__device__ __forceinline__ float rlf(float v){
  return __uint_as_float((unsigned)__builtin_amdgcn_readlane((int)__float_as_uint(v), J));
}
__device__ __forceinline__ float rlfv(float v, int j){   // j compile-time after unroll
  return __uint_as_float((unsigned)__builtin_amdgcn_readlane((int)__float_as_uint(v), j));
}

// acc += f16(lo/hi of wp) * act(f32) + acc, f32 accumulate. act broadcast via SGPR.
__device__ __forceinline__ float mxl(float acc, u32 wp, float a){
  asm("v_fma_mix_f32 %0, %1, %2, %3 op_sel_hi:[1,0,0]"
      : "=v"(acc) : "v"(wp), "s"(a), "0"(acc));
  return acc;
}
__device__ __forceinline__ float mxh(float acc, u32 wp, float a){
  asm("v_fma_mix_f32 %0, %1, %2, %3 op_sel:[1,0,0] op_sel_hi:[1,0,0]"
      : "=v"(acc) : "v"(wp), "s"(a), "0"(acc));
  return acc;
}
// VGPR-act variants (x vectors from LDS)
__device__ __forceinline__ float mxlv(float acc, u32 wp, float a){
  asm("v_fma_mix_f32 %0, %1, %2, %3 op_sel_hi:[1,0,0]"
      : "=v"(acc) : "v"(wp), "v"(a), "0"(acc));
  return acc;
}
__device__ __forceinline__ float mxhv(float acc, u32 wp, float a){
  asm("v_fma_mix_f32 %0, %1, %2, %3 op_sel:[1,0,0] op_sel_hi:[1,0,0]"
      : "=v"(acc) : "v"(wp), "v"(a), "0"(acc));
  return acc;
}

// identical gate math -> bit-identical h wherever computed
__device__ __forceinline__ float gate4(float zi, float zf, float zg, float zo, float& c){
  c = sigf(zf)*c + sigf(zi)*tanhf_(zg);
  return sigf(zo)*tanhf_(c);
}

// 8-elem x+bias dot: w[KB..KB+3] (8 f16) . {v0,v1}
#define XD(a0, a1, KB, v0, v1) { \
  a0 = mxlv(a0, w[(KB)+0], (v0).x); a1 = mxhv(a1, w[(KB)+0], (v0).y); \
  a0 = mxlv(a0, w[(KB)+1], (v0).z); a1 = mxhv(a1, w[(KB)+1], (v0).w); \
  a0 = mxlv(a0, w[(KB)+2], (v1).x); a1 = mxhv(a1, w[(KB)+2], (v1).y); \
  a0 = mxlv(a0, w[(KB)+3], (v1).z); a1 = mxhv(a1, w[(KB)+3], (v1).w); }

// 64-elem dual-row dot (cell row + shared row share f32 broadcasts)
#define MX2(a0, a1, s0, s1, KA, KS, SRC) { _Pragma("unroll") \
  for (int k_ = 0; k_ < 32; k_++){ \
    float e0_ = rlfv(SRC, 2*k_), e1_ = rlfv(SRC, 2*k_+1); \
    a0 = mxl(a0, w[(KA)+k_], e0_); a1 = mxh(a1, w[(KA)+k_], e1_); \
    s0 = mxl(s0, w[(KS)+k_], e0_); s1 = mxh(s1, w[(KS)+k_], e1_); } }

// 64-elem single-row dot
#define MX1(a0, a1, KA, SRC) { _Pragma("unroll") \
  for (int k_ = 0; k_ < 32; k_++){ \
    float e0_ = rlfv(SRC, 2*k_), e1_ = rlfv(SRC, 2*k_+1); \
    a0 = mxl(a0, w[(KA)+k_], e0_); a1 = mxh(a1, w[(KA)+k_], e1_); } }

// 32-elem dot (hh)
#define MXH16(z0, z1, KB, SRC) { _Pragma("unroll") \
  for (int k_ = 0; k_ < 16; k_++){ \
    float e0_ = rlfv(SRC, 2*k_), e1_ = rlfv(SRC, 2*k_+1); \
    z0 = mxl(z0, w[(KB)+k_], e0_); z1 = mxh(z1, w[(KB)+k_], e1_); } }

// MLP: q=relu(b1+W1 h) rows lane&15 (h f32 from lanes 0..31), d=b2+W2 q (q from lanes 0..15)
#define MLPX(HS_, M1B, B1V, M2B, B2V, dres) { \
  float q0_ = (B1V), q1_ = 0.f; \
  _Pragma("unroll") \
  for (int j_ = 0; j_ < 16; j_++){ \
    float e0_ = rlfv(HS_, 2*j_), e1_ = rlfv(HS_, 2*j_+1); \
    q0_ = mxl(q0_, w[(M1B)+j_], e0_); q1_ = mxh(q1_, w[(M1B)+j_], e1_); } \
  float qq_ = fmaxf(q0_+q1_, 0.f); \
  float f0_ = (B2V), f1_ = 0.f; \
  _Pragma("unroll") \
  for (int j_ = 0; j_ < 8; j_++){ \
    float e0_ = rlfv(qq_, 2*j_), e1_ = rlfv(qq_, 2*j_+1); \
    f0_ = mxl(f0_, w[(M2B)+j_], e0_); f1_ = mxh(f1_, w[(M2B)+j_], e1_); } \
  dres = f0_ + f1_; }

__global__ __launch_bounds__(512, 1) void mtinn_kernel(
    const float* __restrict__ x,
    const float* wihs, const float* whhs, const float* bihs, const float* bhhs,
    const float* wiha, const float* whha, const float* biha, const float* bhha,
    const float* wihv, const float* whhv, const float* bihv, const float* bhhv,
    const float* wihp, const float* whhp, const float* bihp, const float* bhhp,
    const float* wa1, const float* ba1, const float* wa2, const float* ba2,
    const float* wv1, const float* bv1, const float* wv2, const float* bv2,
    const float* wp1, const float* bp1, const float* wp2, const float* bp2,
    float* __restrict__ out)
{
  __shared__ __align__(16) float ZS[2][256];   // shared-cell z, double buffered
  __shared__ __align__(16) float ZC[3][128];   // cell z (single buffer: TOP->TAIL)
  __shared__ __align__(16) float HS[64];       // hs(t+1), computed once by w7
  __shared__ __align__(16) float HA[32], HV[32];
  __shared__ __align__(16) float HPb[2][32];   // h_p double-buffered (deferred MLP reads old)
  __shared__ __align__(16) float XL[4][8];     // x ring; slot[7] = 1.0 (bias trick)

  const int tid  = threadIdx.x;
  const int wave = tid >> 6, lane = tid & 63, l = lane & 31;
  const int b    = blockIdx.x;
  const float* xb = x + (size_t)b * NS * NIN;

  // roles (SIMD = wave&3):
  //   wave | phase A                     | phase B
  //   w0   | x-prefetch issue            | TAIL (att/vel/pos gates + att,vel MLPs)
  //   w4   | deferred POS MLP (t-1)      | idle
  //   w1   | TOP att rows 64-127         | WIN att1 + sh_i
  //   w5   | TOP vel rows 0-63           | WIN vel0
  //   w2   | TOP vel rows 64-127         | WIN vel1 + sh_f
  //   w6   | TOP pos rows 0-63           | WIN pos0 + sh_g
  //   w3   | TOP pos rows 64-127         | WIN pos1
  //   w7   | T_hs (hs once) + TOP att0   | WIN att0 + sh_o
  const bool isWin = (wave != 0 && wave != 4);
  const int  wc    = (wave==1||wave==7) ? 0 : (wave==2||wave==5) ? 1 : 2;
  const int  wrb   = (wave <= 3) ? 64 : 0;
  const bool isSh  = (wave==1 || wave==2 || wave==6 || wave==7);
  const int  qoff  = (wave==1) ? 0 : (wave==2) ? 64 : (wave==6) ? 128 : 192;
  const int  mi = lane & 15, mm = lane % 3;

  // ---- packed f16 register weights, per-wave union ----
  // WIN waves: [0..15] hh | [16..47] hs | [48..51] x+bias | [52..83] sh-hs | [84..87] sh-x+bias
  // w0: [0..15] m1a | [16..31] m1v | [48..55] m2a | [56..63] m2v | [72..79] velD | [80..87] posD
  // w4: [0..15] m1p | [16..23] m2p
  u32 w[88];
#pragma unroll
  for (int i = 0; i < 88; i++) w[i] = 0u;
  float b1a=0.f,b2a=0.f,b1v=0.f,b2v=0.f,b1p=0.f,b2p=0.f;

  if (isWin){
    const float* wih = (wc==0) ? wiha : (wc==1) ? wihv : wihp;
    const float* whh = (wc==0) ? whha : (wc==1) ? whhv : whhp;
    const float* bi  = (wc==0) ? biha : (wc==1) ? bihv : bihp;
    const float* bh  = (wc==0) ? bhha : (wc==1) ? bhhv : bhhp;
    const int L = (wc==0) ? 71 : (wc==1) ? 74 : 67;
    const int r = wrb + lane;
#pragma unroll
    for (int k=0;k<16;k++) w[k] = pkh(whh[r*32+2*k], whh[r*32+2*k+1]);
#pragma unroll
    for (int k=0;k<32;k++) w[16+k] = pkh(wih[r*L+2*k], wih[r*L+2*k+1]);
    const float bsum = bi[r] + bh[r];
    if (wc==0){
      w[48]=pkh(wih[r*L+64],wih[r*L+65]); w[49]=pkh(wih[r*L+66],wih[r*L+67]);
      w[50]=pkh(wih[r*L+68],wih[r*L+69]); w[51]=pkh(wih[r*L+70], bsum);
    } else if (wc==1){
      w[48]=pkh(wih[r*L+67],wih[r*L+68]); w[49]=pkh(wih[r*L+69],wih[r*L+70]);
      w[50]=pkh(wih[r*L+71],wih[r*L+72]); w[51]=pkh(wih[r*L+73], bsum);
    } else {
      w[51]=pkh(0.f, bsum);                     // pos: no x-weights
    }
  }
  if (isSh){
    const int r = qoff + lane;
#pragma unroll
    for (int k=0;k<32;k++) w[52+k] = pkh(whhs[r*64+2*k], whhs[r*64+2*k+1]);
    w[84]=pkh(wihs[r*7+0],wihs[r*7+1]); w[85]=pkh(wihs[r*7+2],wihs[r*7+3]);
    w[86]=pkh(wihs[r*7+4],wihs[r*7+5]); w[87]=pkh(wihs[r*7+6], bihs[r]+bhhs[r]);
  }
  if (wave == 0){
#pragma unroll
    for (int k=0;k<16;k++){
      w[k]    = pkh(wa1[mi*32+2*k], wa1[mi*32+2*k+1]);
      w[16+k] = pkh(wv1[mi*32+2*k], wv1[mi*32+2*k+1]);
    }
#pragma unroll
    for (int k=0;k<8;k++){
      w[48+k] = pkh(wa2[mm*16+2*k], wa2[mm*16+2*k+1]);
      w[56+k] = pkh(wv2[mm*16+2*k], wv2[mm*16+2*k+1]);
    }
#pragma unroll
    for (int g=0; g<4; g++){
      int rr = g*32 + l;
      w[72+2*g]   = pkh(wihv[rr*74+64], wihv[rr*74+65]);
      w[72+2*g+1] = pkh(wihv[rr*74+66], 0.f);
      w[80+2*g]   = pkh(wihp[rr*67+64], wihp[rr*67+65]);
      w[80+2*g+1] = pkh(wihp[rr*67+66], 0.f);
    }
    b1a=ba1[mi]; b2a=ba2[mm]; b1v=bv1[mi]; b2v=bv2[mm];
  }
  if (wave == 4){
#pragma unroll
    for (int k=0;k<16;k++) w[k] = pkh(wp1[mi*32+2*k], wp1[mi*32+2*k+1]);
#pragma unroll
    for (int k=0;k<8;k++)  w[16+k] = pkh(wp2[mm*16+2*k], wp2[mm*16+2*k+1]);
    b1p=bp1[mi]; b2p=bp2[mm];
  }

  // ---- LDS init ----
  if (tid < 32) HA[tid]=0.f;
  else if (tid < 64)  HV[tid-32]=0.f;
  else if (tid < 96)  HPb[0][tid-64]=0.f;
  else if (tid < 128) HPb[1][tid-96]=0.f;
  if (tid < 8){
    XL[0][tid] = (tid<7) ? xb[tid]         : 1.f;
    XL[1][tid] = (tid<7) ? xb[NIN+tid]     : 1.f;
    XL[2][tid] = (tid<7) ? xb[2*NIN+tid]   : 1.f;
    XL[3][tid] = 1.f;
  }
  __syncthreads();

  // ---- prologue: zS(0) ----
  if (isSh){
    const float4* X0 = (const float4*)XL[0];
    float4 xa = X0[0], xb4 = X0[1];
    float s0=0.f, s1=0.f; XD(s0,s1,84,xa,xb4);
    ZS[0][qoff + lane] = s0 + s1;
  }
  __syncthreads();

  float c_s = 0.f;                          // live in w7 (T_hs); others' copies unused after prologue
  float c_a = 0.f, c_v = 0.f, c_p = 0.f;    // wave 0
  float zpart = 0.f;

  // ---- prologue: hs(0), zpart(0), zS(1) ----
  if (isWin){
    float zi_=ZS[0][lane], zf_=ZS[0][64+lane], zg_=ZS[0][128+lane], zo_=ZS[0][192+lane];
    float hsv = gate4(zi_,zf_,zg_,zo_, c_s);
    const float4* X0 = (const float4*)XL[0];
    float4 xa = X0[0], xb4 = X0[1];
    float a0=0.f, a1=0.f; XD(a0,a1,48,xa,xb4);
    if (isSh){
      const float4* X1 = (const float4*)XL[1];
      float4 xc = X1[0], xd = X1[1];
      float s0=0.f, s1=0.f; XD(s0,s1,84,xc,xd);
      MX2(a0,a1,s0,s1,16,52,hsv);
      ZS[1][qoff + lane] = s0 + s1;
    } else {
      MX1(a0,a1,16,hsv);
    }
    zpart = a0 + a1;
  }
  __syncthreads();

  // ================= pipelined recurrence =================
#pragma unroll 1
  for (int t = 0; t < NS; t++){
    float xpre = 0.f;
    // ---- PHASE A ----
    if (wave == 0){
      if (lane < 7){
        const int tf = (t+3 < NS) ? t+3 : NS-1;
        xpre = xb[(size_t)tf*NIN + lane];
      }
    } else if (wave == 4){
      if (t > 0){                                     // deferred POS MLP for step t-1
        float hp_ = HPb[(t^1)&1][l];
        float dP; MLPX(hp_, 0, b1p, 16, b2p, dP);
        if (lane < 3) out[((size_t)b*NS + (t-1))*9 + 6 + lane] = dP;
      }
    } else {
      // TOP: z(t) = zpart(t) + Whh . h(t-1)   (h read from LDS, no gate replay)
      const float* Hsrc = (wc==0) ? HA : (wc==1) ? HV : HPb[(t^1)&1];
      float h = Hsrc[l];
      if (wave == 7){                                 // T_hs: hs(t+1), computed once
        const float* Zsrc = ZS[(t+1)&1];
        float zi_=Zsrc[lane], zf_=Zsrc[64+lane], zg_=Zsrc[128+lane], zo_=Zsrc[192+lane];
        float hsv2 = gate4(zi_,zf_,zg_,zo_, c_s);
        HS[lane] = hsv2;
      }
      float z0 = zpart, z1 = 0.f;
      MXH16(z0,z1,0,h);
      ZC[wc][wrb + lane] = z0 + z1;
    }
    __syncthreads();   // #1 : ZC(t), HS(t+1) visible

    // ---- PHASE B ----
    if (wave == 0){
      // ================= TAIL =================
      __builtin_amdgcn_s_setprio(1);
      float zai=ZC[0][l], zaf=ZC[0][32+l], zag=ZC[0][64+l], zao=ZC[0][96+l];
      float zvi=ZC[1][l], zvf=ZC[1][32+l], zvg=ZC[1][64+l], zvo=ZC[1][96+l];
      float zpi=ZC[2][l], zpf=ZC[2][32+l], zpg=ZC[2][64+l], zpo=ZC[2][96+l];
      float* ob = out + ((size_t)b*NS + t)*9;
      // ATT
      float ha = gate4(zai,zaf,zag,zao, c_a);
      if (lane < 32) HA[lane] = ha;
      float dA; MLPX(ha, 0, b1a, 48, b2a, dA);
      if (lane < 3) ob[lane] = dA;
      float dx=rlf<0>(dA), dy=rlf<1>(dA), dz=rlf<2>(dA);
      // VEL (+ d_att columns)
      zvi = mxl(zvi, w[72], dx); zvi = mxh(zvi, w[72], dy); zvi = mxl(zvi, w[73], dz);
      zvf = mxl(zvf, w[74], dx); zvf = mxh(zvf, w[74], dy); zvf = mxl(zvf, w[75], dz);
      zvg = mxl(zvg, w[76], dx); zvg = mxh(zvg, w[76], dy); zvg = mxl(zvg, w[77], dz);
      zvo = mxl(zvo, w[78], dx); zvo = mxh(zvo, w[78], dy); zvo = mxl(zvo, w[79], dz);
      float hv = gate4(zvi,zvf,zvg,zvo, c_v);
      if (lane < 32) HV[lane] = hv;
      float dV; MLPX(hv, 16, b1v, 56, b2v, dV);
      if (lane < 3) ob[3+lane] = dV;
      dx=rlf<0>(dV); dy=rlf<1>(dV); dz=rlf<2>(dV);
      // POS (+ d_vel columns); MLP deferred to w4 next phase A
      zpi = mxl(zpi, w[80], dx); zpi = mxh(zpi, w[80], dy); zpi = mxl(zpi, w[81], dz);
      zpf = mxl(zpf, w[82], dx); zpf = mxh(zpf, w[82], dy); zpf = mxl(zpf, w[83], dz);
      zpg = mxl(zpg, w[84], dx); zpg = mxh(zpg, w[84], dy); zpg = mxl(zpg, w[85], dz);
      zpo = mxl(zpo, w[86], dx); zpo = mxh(zpo, w[86], dy); zpo = mxl(zpo, w[87], dz);
      float hp_ = gate4(zpi,zpf,zpg,zpo, c_p);
      if (lane < 32) HPb[t&1][lane] = hp_;
      __builtin_amdgcn_s_setprio(0);
      if (lane < 7) XL[(t+3)&3][lane] = xpre;          // prefetch landed
    } else if (isWin){
      // ============ WIN: zpart(t+1), zS(t+2) ============
      float hsv = HS[lane];
      const float4* X1 = (const float4*)XL[(t+1)&3];
      float4 xa = X1[0], xb4 = X1[1];
      float a0=0.f, a1=0.f; XD(a0,a1,48,xa,xb4);
      if (isSh){
        const float4* X2 = (const float4*)XL[(t+2)&3];
        float4 xc = X2[0], xd = X2[1];
        float s0=0.f, s1=0.f; XD(s0,s1,84,xc,xd);
        MX2(a0,a1,s0,s1,16,52,hsv);
        ZS[t&1][qoff + lane] = s0 + s1;
      } else {
        MX1(a0,a1,16,hsv);
      }
      zpart = a0 + a1;
    }
    __syncthreads();   // #2
  }

  // ---- epilogue: POS MLP for t = NS-1 ----
  if (wave == 4){
    float hp_ = HPb[(NS-1)&1][l];
    float dP; MLPX(hp_, 0, b1p, 16, b2p, dP);
    if (lane < 3) out[((size_t)b*NS + (NS-1))*9 + 6 + lane] = dP;
  }
}

extern "C" void kernel_launch(void* const* d_in, const int* in_sizes, int n_in,
                              void* d_out, int out_size, void* d_ws, size_t ws_size,
                              hipStream_t stream) {
  (void)in_sizes; (void)n_in; (void)d_ws; (void)ws_size; (void)out_size;
  const float* X    = (const float*)d_in[0];
  const float* Wihs = (const float*)d_in[1];
  const float* Whhs = (const float*)d_in[2];
  const float* Bihs = (const float*)d_in[3];
  const float* Bhhs = (const float*)d_in[4];
  const float* Wiha = (const float*)d_in[5];
  const float* Whha = (const float*)d_in[6];
  const float* Biha = (const float*)d_in[7];
  const float* Bhha = (const float*)d_in[8];
  const float* Wihv = (const float*)d_in[9];
  const float* Whhv = (const float*)d_in[10];
  const float* Bihv = (const float*)d_in[11];
  const float* Bhhv = (const float*)d_in[12];
  const float* Wihp = (const float*)d_in[13];
  const float* Whhp = (const float*)d_in[14];
  const float* Bihp = (const float*)d_in[15];
  const float* Bhhp = (const float*)d_in[16];
  const float* Wa1  = (const float*)d_in[17];
  const float* Ba1  = (const float*)d_in[18];
  const float* Wa2  = (const float*)d_in[19];
  const float* Ba2  = (const float*)d_in[20];
  const float* Wv1  = (const float*)d_in[21];
  const float* Bv1  = (const float*)d_in[22];
  const float* Wv2  = (const float*)d_in[23];
  const float* Bv2  = (const float*)d_in[24];
  const float* Wp1  = (const float*)d_in[25];
  const float* Bp1  = (const float*)d_in[26];
  const float* Wp2  = (const float*)d_in[27];
  const float* Bp2  = (const float*)d_in[28];
  float* OUTP = (float*)d_out;

  mtinn_kernel<<<dim3(NB), dim3(512), 0, stream>>>(
      X, Wihs, Whhs, Bihs, Bhhs,
      Wiha, Whha, Biha, Bhha,
      Wihv, Whhv, Bihv, Bhhv,
      Wihp, Whhp, Bihp, Bhhp,
      Wa1, Ba1, Wa2, Ba2, Wv1, Bv1, Wv2, Bv2, Wp1, Bp1, Wp2, Bp2,
      OUTP);
}

// Round 12
// 2816.525 us; speedup vs baseline: 11.0989x; 1.0195x over previous
//
#include <hip/hip_runtime.h>

typedef unsigned int u32;

#define NIN 7
#define NB 256
#define NS 2048

__device__ __forceinline__ float fastrcp(float x){ return __builtin_amdgcn_rcpf(x); }
__device__ __forceinline__ float sigf(float x){ return fastrcp(1.f + __expf(-x)); }
__device__ __forceinline__ float tanhf_(float x){ return 1.f - 2.f*fastrcp(1.f + __expf(2.f*x)); }

// RNE f16 pack (v_cvt_f16_f32 is RNE; activations stay f32 everywhere)
__device__ __forceinline__ u32 pkh(float a, float b){
  unsigned short ua = __builtin_bit_cast(unsigned short, (_Float16)a);
  unsigned short ub = __builtin_bit_cast(unsigned short, (_Float16)b);
  return (u32)ua | ((u32)ub << 16);
}

template<int J>
__device__ __forceinline__ float rlf(float v){
  return __uint_as_float((unsigned)__builtin_amdgcn_readlane((int)__float_as_uint(v), J));
}
__device__ __forceinline__ float rlfv(float v, int j){   // j compile-time after unroll
  return __uint_as_float((unsigned)__builtin_amdgcn_readlane((int)__float_as_uint(v), j));
}

// acc += f16(lo/hi of wp) * act(f32) + acc, f32 accumulate.
__device__ __forceinline__ float mxl(float acc, u32 wp, float a){
  asm("v_fma_mix_f32 %0, %1, %2, %3 op_sel_hi:[1,0,0]"
      : "=v"(acc) : "v"(wp), "s"(a), "0"(acc));
  return acc;
}
__device__ __forceinline__ float mxh(float acc, u32 wp, float a){
  asm("v_fma_mix_f32 %0, %1, %2, %3 op_sel:[1,0,0] op_sel_hi:[1,0,0]"
      : "=v"(acc) : "v"(wp), "s"(a), "0"(acc));
  return acc;
}
__device__ __forceinline__ float mxlv(float acc, u32 wp, float a){
  asm("v_fma_mix_f32 %0, %1, %2, %3 op_sel_hi:[1,0,0]"
      : "=v"(acc) : "v"(wp), "v"(a), "0"(acc));
  return acc;
}
__device__ __forceinline__ float mxhv(float acc, u32 wp, float a){
  asm("v_fma_mix_f32 %0, %1, %2, %3 op_sel:[1,0,0] op_sel_hi:[1,0,0]"
      : "=v"(acc) : "v"(wp), "v"(a), "0"(acc));
  return acc;
}

// identical gate math -> bit-identical h wherever computed
__device__ __forceinline__ float gate4(float zi, float zf, float zg, float zo, float& c){
  c = sigf(zf)*c + sigf(zi)*tanhf_(zg);
  return sigf(zo)*tanhf_(c);
}

// 8-elem x+bias dot: w[KB..KB+3] (8 f16) . {v0,v1}
#define XD(a0, a1, KB, v0, v1) { \
  a0 = mxlv(a0, w[(KB)+0], (v0).x); a1 = mxhv(a1, w[(KB)+0], (v0).y); \
  a0 = mxlv(a0, w[(KB)+1], (v0).z); a1 = mxhv(a1, w[(KB)+1], (v0).w); \
  a0 = mxlv(a0, w[(KB)+2], (v1).x); a1 = mxhv(a1, w[(KB)+2], (v1).y); \
  a0 = mxlv(a0, w[(KB)+3], (v1).z); a1 = mxhv(a1, w[(KB)+3], (v1).w); }

// ---- LDS-broadcast dots (uniform float4 reads ride the LDS pipe) ----
// 64-elem dual-row dot; H4 = uniform float4* over 64 activations
#define LMX2(a0, a1, s0, s1, KA, KS, H4) { _Pragma("unroll") \
  for (int c_ = 0; c_ < 16; c_++){ \
    float4 h_ = (H4)[c_]; \
    a0 = mxlv(a0, w[(KA)+2*c_],   h_.x); a1 = mxhv(a1, w[(KA)+2*c_],   h_.y); \
    a0 = mxlv(a0, w[(KA)+2*c_+1], h_.z); a1 = mxhv(a1, w[(KA)+2*c_+1], h_.w); \
    s0 = mxlv(s0, w[(KS)+2*c_],   h_.x); s1 = mxhv(s1, w[(KS)+2*c_],   h_.y); \
    s0 = mxlv(s0, w[(KS)+2*c_+1], h_.z); s1 = mxhv(s1, w[(KS)+2*c_+1], h_.w); } }

// 64-elem single-row dot
#define LMX1(a0, a1, KA, H4) { _Pragma("unroll") \
  for (int c_ = 0; c_ < 16; c_++){ \
    float4 h_ = (H4)[c_]; \
    a0 = mxlv(a0, w[(KA)+2*c_],   h_.x); a1 = mxhv(a1, w[(KA)+2*c_],   h_.y); \
    a0 = mxlv(a0, w[(KA)+2*c_+1], h_.z); a1 = mxhv(a1, w[(KA)+2*c_+1], h_.w); } }

// 32-elem dot (hh)
#define LMXH(z0, z1, KB, H4) { _Pragma("unroll") \
  for (int c_ = 0; c_ < 8; c_++){ \
    float4 h_ = (H4)[c_]; \
    z0 = mxlv(z0, w[(KB)+2*c_],   h_.x); z1 = mxhv(z1, w[(KB)+2*c_],   h_.y); \
    z0 = mxlv(z0, w[(KB)+2*c_+1], h_.z); z1 = mxhv(z1, w[(KB)+2*c_+1], h_.w); } }

// ---- readlane dots (prologue + TAIL/w4, where no co-wave overlap exists) ----
#define MX2(a0, a1, s0, s1, KA, KS, SRC) { _Pragma("unroll") \
  for (int k_ = 0; k_ < 32; k_++){ \
    float e0_ = rlfv(SRC, 2*k_), e1_ = rlfv(SRC, 2*k_+1); \
    a0 = mxl(a0, w[(KA)+k_], e0_); a1 = mxh(a1, w[(KA)+k_], e1_); \
    s0 = mxl(s0, w[(KS)+k_], e0_); s1 = mxh(s1, w[(KS)+k_], e1_); } }

#define MX1(a0, a1, KA, SRC) { _Pragma("unroll") \
  for (int k_ = 0; k_ < 32; k_++){ \
    float e0_ = rlfv(SRC, 2*k_), e1_ = rlfv(SRC, 2*k_+1); \
    a0 = mxl(a0, w[(KA)+k_], e0_); a1 = mxh(a1, w[(KA)+k_], e1_); } }

// MLP: q=relu(b1+W1 h) rows lane&15 (h f32 from lanes 0..31), d=b2+W2 q (q from lanes 0..15)
#define MLPX(HS_, M1B, B1V, M2B, B2V, dres) { \
  float q0_ = (B1V), q1_ = 0.f; \
  _Pragma("unroll") \
  for (int j_ = 0; j_ < 16; j_++){ \
    float e0_ = rlfv(HS_, 2*j_), e1_ = rlfv(HS_, 2*j_+1); \
    q0_ = mxl(q0_, w[(M1B)+j_], e0_); q1_ = mxh(q1_, w[(M1B)+j_], e1_); } \
  float qq_ = fmaxf(q0_+q1_, 0.f); \
  float f0_ = (B2V), f1_ = 0.f; \
  _Pragma("unroll") \
  for (int j_ = 0; j_ < 8; j_++){ \
    float e0_ = rlfv(qq_, 2*j_), e1_ = rlfv(qq_, 2*j_+1); \
    f0_ = mxl(f0_, w[(M2B)+j_], e0_); f1_ = mxh(f1_, w[(M2B)+j_], e1_); } \
  dres = f0_ + f1_; }

__global__ __launch_bounds__(512, 2) void mtinn_kernel(
    const float* __restrict__ x,
    const float* wihs, const float* whhs, const float* bihs, const float* bhhs,
    const float* wiha, const float* whha, const float* biha, const float* bhha,
    const float* wihv, const float* whhv, const float* bihv, const float* bhhv,
    const float* wihp, const float* whhp, const float* bihp, const float* bhhp,
    const float* wa1, const float* ba1, const float* wa2, const float* ba2,
    const float* wv1, const float* bv1, const float* wv2, const float* bv2,
    const float* wp1, const float* bp1, const float* wp2, const float* bp2,
    float* __restrict__ out)
{
  __shared__ __align__(16) float ZS[2][256];   // shared-cell z, double buffered
  __shared__ __align__(16) float ZC[3][128];   // cell z (single buffer: TOP->TAIL)
  __shared__ __align__(16) float HS[64];       // hs(t+1), computed once by w4
  __shared__ __align__(16) float HA[32], HV[32];
  __shared__ __align__(16) float HPb[2][32];   // h_p double-buffered (deferred MLP reads old)
  __shared__ __align__(16) float XL[4][8];     // x ring; slot[7] = 1.0 (bias trick)

  const int tid  = threadIdx.x;
  const int wave = tid >> 6, lane = tid & 63, l = lane & 31;
  const int b    = blockIdx.x;
  const float* xb = x + (size_t)b * NS * NIN;

  // roles (SIMD = wave&3):
  //   wave | phase A                        | phase B
  //   w0   | x-prefetch issue               | TAIL (3 gates + att,vel MLPs)
  //   w4   | deferred POS MLP (t-1) + T_hs  | idle
  //   w1   | TOP att rows 64-127            | WIN att1 + sh_i
  //   w5   | TOP vel rows 0-63              | WIN vel0
  //   w2   | TOP vel rows 64-127            | WIN vel1 + sh_f
  //   w6   | TOP pos rows 0-63              | WIN pos0 + sh_g
  //   w3   | TOP pos rows 64-127            | WIN pos1
  //   w7   | TOP att rows 0-63              | WIN att0 + sh_o
  const bool isWin = (wave != 0 && wave != 4);
  const int  wc    = (wave==1||wave==7) ? 0 : (wave==2||wave==5) ? 1 : 2;
  const int  wrb   = (wave <= 3) ? 64 : 0;
  const bool isSh  = (wave==1 || wave==2 || wave==6 || wave==7);
  const int  qoff  = (wave==1) ? 0 : (wave==2) ? 64 : (wave==6) ? 128 : 192;
  const int  mi = lane & 15, mm = lane % 3;

  // ---- packed f16 register weights, per-wave union ----
  // WIN waves: [0..15] hh | [16..47] hs | [48..51] x+bias | [52..83] sh-hs | [84..87] sh-x+bias
  // w0: [0..15] m1a | [16..31] m1v | [48..55] m2a | [56..63] m2v | [72..79] velD | [80..87] posD
  // w4: [0..15] m1p | [16..23] m2p
  u32 w[88];
#pragma unroll
  for (int i = 0; i < 88; i++) w[i] = 0u;
  float b1a=0.f,b2a=0.f,b1v=0.f,b2v=0.f,b1p=0.f,b2p=0.f;

  if (isWin){
    const float* wih = (wc==0) ? wiha : (wc==1) ? wihv : wihp;
    const float* whh = (wc==0) ? whha : (wc==1) ? whhv : whhp;
    const float* bi  = (wc==0) ? biha : (wc==1) ? bihv : bihp;
    const float* bh  = (wc==0) ? bhha : (wc==1) ? bhhv : bhhp;
    const int L = (wc==0) ? 71 : (wc==1) ? 74 : 67;
    const int r = wrb + lane;
#pragma unroll
    for (int k=0;k<16;k++) w[k] = pkh(whh[r*32+2*k], whh[r*32+2*k+1]);
#pragma unroll
    for (int k=0;k<32;k++) w[16+k] = pkh(wih[r*L+2*k], wih[r*L+2*k+1]);
    const float bsum = bi[r] + bh[r];
    if (wc==0){
      w[48]=pkh(wih[r*L+64],wih[r*L+65]); w[49]=pkh(wih[r*L+66],wih[r*L+67]);
      w[50]=pkh(wih[r*L+68],wih[r*L+69]); w[51]=pkh(wih[r*L+70], bsum);
    } else if (wc==1){
      w[48]=pkh(wih[r*L+67],wih[r*L+68]); w[49]=pkh(wih[r*L+69],wih[r*L+70]);
      w[50]=pkh(wih[r*L+71],wih[r*L+72]); w[51]=pkh(wih[r*L+73], bsum);
    } else {
      w[51]=pkh(0.f, bsum);                     // pos: no x-weights
    }
  }
  if (isSh){
    const int r = qoff + lane;
#pragma unroll
    for (int k=0;k<32;k++) w[52+k] = pkh(whhs[r*64+2*k], whhs[r*64+2*k+1]);
    w[84]=pkh(wihs[r*7+0],wihs[r*7+1]); w[85]=pkh(wihs[r*7+2],wihs[r*7+3]);
    w[86]=pkh(wihs[r*7+4],wihs[r*7+5]); w[87]=pkh(wihs[r*7+6], bihs[r]+bhhs[r]);
  }
  if (wave == 0){
#pragma unroll
    for (int k=0;k<16;k++){
      w[k]    = pkh(wa1[mi*32+2*k], wa1[mi*32+2*k+1]);
      w[16+k] = pkh(wv1[mi*32+2*k], wv1[mi*32+2*k+1]);
    }
#pragma unroll
    for (int k=0;k<8;k++){
      w[48+k] = pkh(wa2[mm*16+2*k], wa2[mm*16+2*k+1]);
      w[56+k] = pkh(wv2[mm*16+2*k], wv2[mm*16+2*k+1]);
    }
#pragma unroll
    for (int g=0; g<4; g++){
      int rr = g*32 + l;
      w[72+2*g]   = pkh(wihv[rr*74+64], wihv[rr*74+65]);
      w[72+2*g+1] = pkh(wihv[rr*74+66], 0.f);
      w[80+2*g]   = pkh(wihp[rr*67+64], wihp[rr*67+65]);
      w[80+2*g+1] = pkh(wihp[rr*67+66], 0.f);
    }
    b1a=ba1[mi]; b2a=ba2[mm]; b1v=bv1[mi]; b2v=bv2[mm];
  }
  if (wave == 4){
#pragma unroll
    for (int k=0;k<16;k++) w[k] = pkh(wp1[mi*32+2*k], wp1[mi*32+2*k+1]);
#pragma unroll
    for (int k=0;k<8;k++)  w[16+k] = pkh(wp2[mm*16+2*k], wp2[mm*16+2*k+1]);
    b1p=bp1[mi]; b2p=bp2[mm];
  }

  // ---- LDS init ----
  if (tid < 32) HA[tid]=0.f;
  else if (tid < 64)  HV[tid-32]=0.f;
  else if (tid < 96)  HPb[0][tid-64]=0.f;
  else if (tid < 128) HPb[1][tid-96]=0.f;
  if (tid < 8){
    XL[0][tid] = (tid<7) ? xb[tid]         : 1.f;
    XL[1][tid] = (tid<7) ? xb[NIN+tid]     : 1.f;
    XL[2][tid] = (tid<7) ? xb[2*NIN+tid]   : 1.f;
    XL[3][tid] = 1.f;
  }
  __syncthreads();

  // ---- prologue: zS(0) ----
  if (isSh){
    const float4* X0 = (const float4*)XL[0];
    float4 xa = X0[0], xb4 = X0[1];
    float s0=0.f, s1=0.f; XD(s0,s1,84,xa,xb4);
    ZS[0][qoff + lane] = s0 + s1;
  }
  __syncthreads();

  float c_s = 0.f;                          // live in w4 (T_hs)
  float c_a = 0.f, c_v = 0.f, c_p = 0.f;    // wave 0
  float zpart = 0.f;

  // ---- prologue: hs(0), zpart(0), zS(1); w4 warms its c_s ----
  if (isWin){
    float zi_=ZS[0][lane], zf_=ZS[0][64+lane], zg_=ZS[0][128+lane], zo_=ZS[0][192+lane];
    float hsv = gate4(zi_,zf_,zg_,zo_, c_s);
    const float4* X0 = (const float4*)XL[0];
    float4 xa = X0[0], xb4 = X0[1];
    float a0=0.f, a1=0.f; XD(a0,a1,48,xa,xb4);
    if (isSh){
      const float4* X1 = (const float4*)XL[1];
      float4 xc = X1[0], xd = X1[1];
      float s0=0.f, s1=0.f; XD(s0,s1,84,xc,xd);
      MX2(a0,a1,s0,s1,16,52,hsv);
      ZS[1][qoff + lane] = s0 + s1;
    } else {
      MX1(a0,a1,16,hsv);
    }
    zpart = a0 + a1;
  } else if (wave == 4){
    float zi_=ZS[0][lane], zf_=ZS[0][64+lane], zg_=ZS[0][128+lane], zo_=ZS[0][192+lane];
    gate4(zi_,zf_,zg_,zo_, c_s);              // establish c_s(0); h discarded
  }
  __syncthreads();

  // ================= pipelined recurrence =================
#pragma unroll 1
  for (int t = 0; t < NS; t++){
    float xpre = 0.f;
    // ---- PHASE A ----
    if (wave == 0){
      if (lane < 7){
        const int tf = (t+3 < NS) ? t+3 : NS-1;
        xpre = xb[(size_t)tf*NIN + lane];
      }
    } else if (wave == 4){
      // T_hs: hs(t+1) from zS(t+1), computed once
      const float* Zsrc = ZS[(t+1)&1];
      float zi_=Zsrc[lane], zf_=Zsrc[64+lane], zg_=Zsrc[128+lane], zo_=Zsrc[192+lane];
      float hsv2 = gate4(zi_,zf_,zg_,zo_, c_s);
      HS[lane] = hsv2;
      if (t > 0){                                     // deferred POS MLP for step t-1
        float hp_ = HPb[(t^1)&1][l];
        float dP; MLPX(hp_, 0, b1p, 16, b2p, dP);
        if (lane < 3) out[((size_t)b*NS + (t-1))*9 + 6 + lane] = dP;
      }
    } else {
      // TOP: z(t) = zpart(t) + Whh . h(t-1)   (h via uniform LDS float4 reads)
      const float4* H4 = (const float4*)((wc==0) ? HA : (wc==1) ? HV : HPb[(t^1)&1]);
      float z0 = zpart, z1 = 0.f;
      LMXH(z0,z1,0,H4);
      ZC[wc][wrb + lane] = z0 + z1;
    }
    __syncthreads();   // #1 : ZC(t), HS(t+1) visible

    // ---- PHASE B ----
    if (wave == 0){
      // ================= TAIL =================
      __builtin_amdgcn_s_setprio(1);
      float zai=ZC[0][l], zaf=ZC[0][32+l], zag=ZC[0][64+l], zao=ZC[0][96+l];
      float zvi=ZC[1][l], zvf=ZC[1][32+l], zvg=ZC[1][64+l], zvo=ZC[1][96+l];
      float zpi=ZC[2][l], zpf=ZC[2][32+l], zpg=ZC[2][64+l], zpo=ZC[2][96+l];
      float* ob = out + ((size_t)b*NS + t)*9;
      // ATT
      float ha = gate4(zai,zaf,zag,zao, c_a);
      if (lane < 32) HA[lane] = ha;
      float dA; MLPX(ha, 0, b1a, 48, b2a, dA);
      if (lane < 3) ob[lane] = dA;
      float dx=rlf<0>(dA), dy=rlf<1>(dA), dz=rlf<2>(dA);
      // VEL (+ d_att columns)
      zvi = mxl(zvi, w[72], dx); zvi = mxh(zvi, w[72], dy); zvi = mxl(zvi, w[73], dz);
      zvf = mxl(zvf, w[74], dx); zvf = mxh(zvf, w[74], dy); zvf = mxl(zvf, w[75], dz);
      zvg = mxl(zvg, w[76], dx); zvg = mxh(zvg, w[76], dy); zvg = mxl(zvg, w[77], dz);
      zvo = mxl(zvo, w[78], dx); zvo = mxh(zvo, w[78], dy); zvo = mxl(zvo, w[79], dz);
      float hv = gate4(zvi,zvf,zvg,zvo, c_v);
      if (lane < 32) HV[lane] = hv;
      float dV; MLPX(hv, 16, b1v, 56, b2v, dV);
      if (lane < 3) ob[3+lane] = dV;
      dx=rlf<0>(dV); dy=rlf<1>(dV); dz=rlf<2>(dV);
      // POS (+ d_vel columns); MLP deferred to w4 next phase A
      zpi = mxl(zpi, w[80], dx); zpi = mxh(zpi, w[80], dy); zpi = mxl(zpi, w[81], dz);
      zpf = mxl(zpf, w[82], dx); zpf = mxh(zpf, w[82], dy); zpf = mxl(zpf, w[83], dz);
      zpg = mxl(zpg, w[84], dx); zpg = mxh(zpg, w[84], dy); zpg = mxl(zpg, w[85], dz);
      zpo = mxl(zpo, w[86], dx); zpo = mxh(zpo, w[86], dy); zpo = mxl(zpo, w[87], dz);
      float hp_ = gate4(zpi,zpf,zpg,zpo, c_p);
      if (lane < 32) HPb[t&1][lane] = hp_;
      __builtin_amdgcn_s_setprio(0);
      if (lane < 7) XL[(t+3)&3][lane] = xpre;          // prefetch landed
    } else if (isWin){
      // ============ WIN: zpart(t+1), zS(t+2) (hs via uniform LDS reads) ============
      const float4* H4 = (const float4*)HS;
      const float4* X1 = (const float4*)XL[(t+1)&3];
      float4 xa = X1[0], xb4 = X1[1];
      float a0=0.f, a1=0.f; XD(a0,a1,48,xa,xb4);
      if (isSh){
        const float4* X2 = (const float4*)XL[(t+2)&3];
        float4 xc = X2[0], xd = X2[1];
        float s0=0.f, s1=0.f; XD(s0,s1,84,xc,xd);
        LMX2(a0,a1,s0,s1,16,52,H4);
        ZS[t&1][qoff + lane] = s0 + s1;
      } else {
        LMX1(a0,a1,16,H4);
      }
      zpart = a0 + a1;
    }
    __syncthreads();   // #2
  }

  // ---- epilogue: POS MLP for t = NS-1 ----
  if (wave == 4){
    float hp_ = HPb[(NS-1)&1][l];
    float dP; MLPX(hp_, 0, b1p, 16, b2p, dP);
    if (lane < 3) out[((size_t)b*NS + (NS-1))*9 + 6 + lane] = dP;
  }
}

extern "C" void kernel_launch(void* const* d_in, const int* in_sizes, int n_in,
                              void* d_out, int out_size, void* d_ws, size_t ws_size,
                              hipStream_t stream) {
  (void)in_sizes; (void)n_in; (void)d_ws; (void)ws_size; (void)out_size;
  const float* X    = (const float*)d_in[0];
  const float* Wihs = (const float*)d_in[1];
  const float* Whhs = (const float*)d_in[2];
  const float* Bihs = (const float*)d_in[3];
  const float* Bhhs = (const float*)d_in[4];
  const float* Wiha = (const float*)d_in[5];
  const float* Whha = (const float*)d_in[6];
  const float* Biha = (const float*)d_in[7];
  const float* Bhha = (const float*)d_in[8];
  const float* Wihv = (const float*)d_in[9];
  const float* Whhv = (const float*)d_in[10];
  const float* Bihv = (const float*)d_in[11];
  const float* Bhhv = (const float*)d_in[12];
  const float* Wihp = (const float*)d_in[13];
  const float* Whhp = (const float*)d_in[14];
  const float* Bihp = (const float*)d_in[15];
  const float* Bhhp = (const float*)d_in[16];
  const float* Wa1  = (const float*)d_in[17];
  const float* Ba1  = (const float*)d_in[18];
  const float* Wa2  = (const float*)d_in[19];
  const float* Ba2  = (const float*)d_in[20];
  const float* Wv1  = (const float*)d_in[21];
  const float* Bv1  = (const float*)d_in[22];
  const float* Wv2  = (const float*)d_in[23];
  const float* Bv2  = (const float*)d_in[24];
  const float* Wp1  = (const float*)d_in[25];
  const float* Bp1  = (const float*)d_in[26];
  const float* Wp2  = (const float*)d_in[27];
  const float* Bp2  = (const float*)d_in[28];
  float* OUTP = (float*)d_out;

  mtinn_kernel<<<dim3(NB), dim3(512), 0, stream>>>(
      X, Wihs, Whhs, Bihs, Bhhs,
      Wiha, Whha, Biha, Bhha,
      Wihv, Whhv, Bihv, Bhhv,
      Wihp, Whhp, Bihp, Bhhp,
      Wa1, Ba1, Wa2, Ba2, Wv1, Bv1, Wv2, Bv2, Wp1, Bp1, Wp2, Bp2,
      OUTP);
}